// Round 4
// baseline (310.728 us; speedup 1.0000x reference)
//
#include <hip/hip_runtime.h>
#include <math.h>

#define NPTS 65536

using half8   = __attribute__((ext_vector_type(8))) _Float16;
using half4   = __attribute__((ext_vector_type(4))) _Float16;
using floatx4 = __attribute__((ext_vector_type(4))) float;

// ---------------------------------------------------------------------------
// k_prep: weights -> f16 [64 d][1024 kc'] with kc' = c*16 + k (k=15 row zero);
//         features -> f16 table featH[N][64]. Block 0 also zeroes stats.
// ---------------------------------------------------------------------------
__global__ __launch_bounds__(256) void k_prep(
    const float* __restrict__ ow, const float* __restrict__ w,
    const float* __restrict__ feat,
    _Float16* __restrict__ owt, _Float16* __restrict__ wt,
    _Float16* __restrict__ featH, float* __restrict__ stats)
{
  int b = blockIdx.x;
  if (b < 256) {                       // 256*256 == 65536 == 64*1024
    int i = b * 256 + threadIdx.x;
    int d = i >> 10, kc = i & 1023, c = kc >> 4, k = kc & 15;
    owt[i] = (k < 15 && d < 60) ? (_Float16)ow[(k * 64 + c) * 60 + d] : (_Float16)0.f;
    wt[i]  = (k < 15) ? (_Float16)w[(k * 64 + c) * 64 + d] : (_Float16)0.f;
    if (b == 0 && threadIdx.x < 128) stats[threadIdx.x] = 0.f;
  } else {                             // 4096*256 == 1048576 == N*64/4
    int j = (b - 256) * 256 + threadIdx.x;
    float4 f = ((const float4*)feat)[j];
    half4 h = {(_Float16)f.x, (_Float16)f.y, (_Float16)f.z, (_Float16)f.w};
    ((half4*)featH)[j] = h;
  }
}

// ---------------------------------------------------------------------------
// Fused deformable KPConv. 16 pts/block, 4 waves x 4 pts. Round-3 structure:
//  * quarter-K GEMM A-panel (wfh 8448 B), deferred quarters packed f16 (24 regs)
//  * rank-2 neighbors (32,33) via chained MFMA; modulation folded into A rows
//  * batch stats fused into GEMM1 epilogue
// This round:
//  * np4 float4 staging + dot-form influence (d2 = |np|^2+|kp|^2-2 np.kp):
//    1 b128 LDS read + ~8 VALU per neighbor instead of 3 b32 + ~11 VALU.
//  * __launch_bounds__(256, 4): occupancy was pinned at 3 blocks/CU (31%)
//    despite LDS fitting 4 -- push the allocator to a 4-waves/EU (128-reg)
//    budget. Design measures 68 VGPR, fits. Tripwire: WRITE_SIZE must stay
//    ~18 MB; if it balloons the hint re-split the register file (round-1
//    failure mode) and must be reverted.
// LDS total 39488 B -> 4 blocks/CU.
// ---------------------------------------------------------------------------
__global__ __launch_bounds__(256, 4) void k_fused(
    const float* __restrict__ query, const float* __restrict__ support,
    const int* __restrict__ nidx, const _Float16* __restrict__ featH,
    const float* __restrict__ kpts, const float* __restrict__ obias,
    const _Float16* __restrict__ owt, const _Float16* __restrict__ wt,
    float* __restrict__ outx, float* __restrict__ stats)
{
  __shared__ float4                 np4[16][34];     // (dx,dy,dz,|np|^2) 8704B
  __shared__ unsigned short         sidx[16][34];    // 1088B
  __shared__ __align__(16) _Float16 fT[4][64 * 32];  // per-wave transpose 16384B
  __shared__ unsigned int           fx2[4][64];      // per-wave (f32,f33)/c 1024B
  __shared__ __align__(16) _Float16 wfh[16 * 264];   // quarter-K A-panel 8448B
  __shared__ float                  dk[16][60];      // def_kp(45)+mod(15) 3840B

  const int tid  = threadIdx.x;
  const int wave = tid >> 6, lane = tid & 63;
  const int quad = lane >> 4, mm = lane & 15;
  const int base = blockIdx.x * 16;
  _Float16* fTw = fT[wave];
  unsigned int* fTw32 = (unsigned int*)fTw;
  unsigned int* fx2w = fx2[wave];
  const floatx4 fz = {0.f, 0.f, 0.f, 0.f};
  const int me = (mm < 15) ? mm : 14;   // row 15 of conv A is discarded

  // ---- stage neighbor displacements (+|np|^2) + indices ----
  for (int s = tid; s < 544; s += 256) {
    int pt = s / 34, a = s - pt * 34;
    int n = base + pt;
    int id = nidx[n * 34 + a];
    float dx = support[id * 3 + 0] - query[n * 3 + 0];
    float dy = support[id * 3 + 1] - query[n * 3 + 1];
    float dz = support[id * 3 + 2] - query[n * 3 + 2];
    float4 q = {dx, dy, dz, dx * dx + dy * dy + dz * dz};
    np4[pt][a] = q;
    sidx[pt][a] = (unsigned short)id;
  }
  __syncthreads();

  // ---- gather loads (17 row-pairs x 8 chunks = 136 tasks) ----
  auto load_g = [&](int pl, uint4* g0, uint4* g1) {
    #pragma unroll
    for (int it = 0; it < 3; ++it) {
      int task = it * 64 + lane;
      if (task < 136) {
        int rp = task >> 3, ch = task & 7;
        int i0 = (int)sidx[pl][2 * rp], i1 = (int)sidx[pl][2 * rp + 1];
        g0[it] = *(const uint4*)(featH + i0 * 64 + ch * 8);
        g1[it] = *(const uint4*)(featH + i1 * 64 + ch * 8);
      }
    }
  };
  // ---- transpose staged regs -> fTw (rp<16) / fx2w (rp==16) ----
  auto transpose_g = [&](const uint4* g0, const uint4* g1) {
    #pragma unroll
    for (int it = 0; it < 3; ++it) {
      int task = it * 64 + lane;
      if (task < 136) {
        int rp = task >> 3, ch = task & 7;
        const uint* p0 = (const uint*)&g0[it];
        const uint* p1 = (const uint*)&g1[it];
        if (rp < 16) {
          int chunk = rp >> 2, o = rp & 3;
          #pragma unroll
          for (int cc = 0; cc < 8; ++cc) {
            int c  = ch * 8 + cc;
            int pc = chunk ^ ((ch ^ cc) & 3);
            uint v = __builtin_amdgcn_perm(p1[cc >> 1], p0[cc >> 1],
                                           (cc & 1) ? 0x07060302u : 0x05040100u);
            fTw32[c * 16 + pc * 4 + o] = v;
          }
        } else {  // rows 32,33 -> fx2 (lo = f32[c], hi = f33[c])
          #pragma unroll
          for (int cc = 0; cc < 8; ++cc) {
            uint v = __builtin_amdgcn_perm(p1[cc >> 1], p0[cc >> 1],
                                           (cc & 1) ? 0x07060302u : 0x05040100u);
            fx2w[ch * 8 + cc] = v;
          }
        }
      }
    }
  };

  // ---- one conv point: 4x (MFMA nbr0..31 + chained rank-2 MFMA nbr32,33).
  //      modulation pre-folded into A rows (lane row == kernel point).
  //      writes ct0 quarter to wfh, returns ct1..3 packed in hq[3] ----
  auto conv_point = [&](int pl, float kx, float ky, float kz, float modme,
                        half4* hq) {
    float hk = kx * kx + ky * ky + kz * kz;
    half8 a0;
    #pragma unroll
    for (int j = 0; j < 8; ++j) {
      int a = quad * 8 + j;
      float4 q = np4[pl][a];
      float dt = q.x * kx + q.y * ky + q.z * kz;
      float d2 = fmaxf(q.w + hk - 2.f * dt, 0.f);
      a0[j] = (_Float16)(fmaxf(1.f - 2.f * sqrtf(d2), 0.f) * modme);
    }
    // rank-2 rows: virtual k'=0,1 supplied only by quad-0 lanes (row = mm)
    float4 q = np4[pl][32];
    float dt = q.x * kx + q.y * ky + q.z * kz;
    float w32 = fmaxf(1.f - 2.f * sqrtf(fmaxf(q.w + hk - 2.f * dt, 0.f)), 0.f) * modme;
    q = np4[pl][33];
    dt = q.x * kx + q.y * ky + q.z * kz;
    float w33 = fmaxf(1.f - 2.f * sqrtf(fmaxf(q.w + hk - 2.f * dt, 0.f)), 0.f) * modme;
    half8 a2 = {};
    a2[0] = (_Float16)((quad == 0) ? w32 : 0.f);
    a2[1] = (_Float16)((quad == 0) ? w33 : 0.f);
    #pragma unroll
    for (int ct = 0; ct < 4; ++ct) {
      int c  = ct * 16 + mm;
      int pc = quad ^ (((c >> 3) ^ c) & 3);
      half8 b = *(const half8*)(fTw + c * 32 + pc * 8);
      floatx4 acc = __builtin_amdgcn_mfma_f32_16x16x32_f16(a0, b, fz, 0, 0, 0);
      uint fp = fx2w[c];
      half8 b2 = {};
      b2[0] = __builtin_bit_cast(_Float16, (unsigned short)(fp & 0xffffu));
      b2[1] = __builtin_bit_cast(_Float16, (unsigned short)(fp >> 16));
      acc = __builtin_amdgcn_mfma_f32_16x16x32_f16(a2, b2, acc, 0, 0, 0);
      half4 h = {(_Float16)acc[0], (_Float16)acc[1],
                 (_Float16)acc[2], (_Float16)acc[3]};
      if (ct == 0) *(half4*)(wfh + pl * 264 + mm * 16 + quad * 4) = h;
      else         hq[ct - 1] = h;
    }
  };

  // ---- write one held quarter (ct = idx+1) into wfh ----
  auto write_hold = [&](const half4 (*hq)[3], int idx) {
    #pragma unroll
    for (int pp = 0; pp < 4; ++pp)
      *(half4*)(wfh + (wave * 4 + pp) * 264 + mm * 16 + quad * 4) = hq[pp][idx];
  };

  // ---- quarter-K GEMM: 8 k-steps vs bmat rows [64][1024], quarter p ----
  auto gemm_q = [&](const _Float16* bmat, int p, floatx4& A, floatx4& B) {
    const _Float16* brow = bmat + (wave * 16 + mm) * 1024 + p * 256;
    const _Float16* arow = wfh + mm * 264;
    #pragma unroll
    for (int k2 = 0; k2 < 8; ++k2) {
      half8 af = *(const half8*)(arow + k2 * 32 + quad * 8);
      half8 bf = *(const half8*)(brow + k2 * 32 + quad * 8);
      if (k2 & 1) B = __builtin_amdgcn_mfma_f32_16x16x32_f16(af, bf, B, 0, 0, 0);
      else        A = __builtin_amdgcn_mfma_f32_16x16x32_f16(af, bf, A, 0, 0, 0);
    }
  };

  uint4 G0[2][3], G1[2][3];
  half4 hq[4][3];           // deferred quarters, packed f16 (24 VGPRs)
  const float k0x = kpts[me * 3 + 0], k0y = kpts[me * 3 + 1], k0z = kpts[me * 3 + 2];

  // ================= conv0 (rigid kernel points) =================
  {
    load_g(wave * 4, G0[0], G1[0]);
    #pragma unroll
    for (int pp = 0; pp < 4; ++pp) {
      int pl = wave * 4 + pp;
      if (pp < 3) load_g(pl + 1, G0[(pp + 1) & 1], G1[(pp + 1) & 1]);
      transpose_g(G0[pp & 1], G1[pp & 1]);
      conv_point(pl, k0x, k0y, k0z, 1.f, hq[pp]);
    }
  }
  load_g(wave * 4, G0[0], G1[0]);   // prefetch conv1 p0 under GEMM0
  __syncthreads();

  // ================= GEMM0 (4 quarter phases) -> def_kp + modulations ========
  {
    floatx4 A = fz, B = fz;
    gemm_q(owt, 0, A, B);
    __syncthreads(); write_hold(hq, 0); __syncthreads();
    gemm_q(owt, 1, A, B);
    __syncthreads(); write_hold(hq, 1); __syncthreads();
    gemm_q(owt, 2, A, B);
    __syncthreads(); write_hold(hq, 2); __syncthreads();
    gemm_q(owt, 3, A, B);
    int d = wave * 16 + mm;
    float bv = (d < 60) ? obias[d] : 0.f;
    float kv = (d < 45) ? kpts[d] : 0.f;
    #pragma unroll
    for (int r = 0; r < 4; ++r) {
      int pt = quad * 4 + r;
      float v = A[r] + B[r] + bv;
      if (d < 60)
        dk[pt][d] = (d < 45) ? (kv + 0.5f * v)            // def_kp = kp + f0*EXTENT
                             : (2.f / (1.f + expf(-v)));  // modulation
    }
  }
  __syncthreads();   // dk ready; GEMM0 wfh reads done

  // ================= conv1 (deformed kernel points) =================
  #pragma unroll
  for (int pp = 0; pp < 4; ++pp) {
    int pl = wave * 4 + pp;
    if (pp < 3) load_g(pl + 1, G0[(pp + 1) & 1], G1[(pp + 1) & 1]);
    float kx = dk[pl][me * 3 + 0], ky = dk[pl][me * 3 + 1], kz = dk[pl][me * 3 + 2];
    float modme = dk[pl][45 + me];
    transpose_g(G0[pp & 1], G1[pp & 1]);
    conv_point(pl, kx, ky, kz, modme, hq[pp]);
  }
  __syncthreads();

  // ================= GEMM1 (4 quarter phases) -> x + fused batch stats =======
  {
    floatx4 A = fz, B = fz;
    gemm_q(wt, 0, A, B);
    __syncthreads(); write_hold(hq, 0); __syncthreads();
    gemm_q(wt, 1, A, B);
    __syncthreads(); write_hold(hq, 1); __syncthreads();
    gemm_q(wt, 2, A, B);
    __syncthreads(); write_hold(hq, 2); __syncthreads();
    gemm_q(wt, 3, A, B);
    int d = wave * 16 + mm;
    float s1 = 0.f, s2 = 0.f;
    #pragma unroll
    for (int r = 0; r < 4; ++r) {
      float v = A[r] + B[r];
      outx[(base + quad * 4 + r) * 64 + d] = v;
      s1 += v; s2 += v * v;
    }
    s1 += __shfl_xor(s1, 16); s2 += __shfl_xor(s2, 16);
    s1 += __shfl_xor(s1, 32); s2 += __shfl_xor(s2, 32);
    if (lane < 16) {
      atomicAdd(&stats[d], s1);
      atomicAdd(&stats[64 + d], s2);
    }
  }
}

// ---------------------------------------------------------------------------
// BN (batch stats, biased var, eps=1e-6) + LeakyReLU(0.1), in-place
// ---------------------------------------------------------------------------
__global__ __launch_bounds__(256) void k_norm(
    float* __restrict__ x, const float* __restrict__ stats,
    const float* __restrict__ gamma, const float* __restrict__ beta)
{
  const int i = blockIdx.x * 256 + threadIdx.x;
  float4 v = ((float4*)x)[i];
  const int c0 = (i * 4) & 63;
  float o[4] = {v.x, v.y, v.z, v.w};
  #pragma unroll
  for (int j = 0; j < 4; ++j) {
    int c = c0 + j;
    float mean = stats[c] * (1.f / NPTS);
    float var  = stats[64 + c] * (1.f / NPTS) - mean * mean;
    float s = rsqrtf(var + 1e-6f) * gamma[c];
    float y = (o[j] - mean) * s + beta[c];
    o[j] = (y >= 0.f) ? y : 0.1f * y;
  }
  float4 rv = {o[0], o[1], o[2], o[3]};
  ((float4*)x)[i] = rv;
}

// ---------------------------------------------------------------------------
extern "C" void kernel_launch(void* const* d_in, const int* in_sizes, int n_in,
                              void* d_out, int out_size, void* d_ws, size_t ws_size,
                              hipStream_t stream)
{
  const float* query   = (const float*)d_in[0];
  const float* support = (const float*)d_in[1];
  const int*   nidx    = (const int*)d_in[2];
  const float* feat    = (const float*)d_in[3];
  const float* weight  = (const float*)d_in[4];
  const float* oweight = (const float*)d_in[5];
  const float* obias   = (const float*)d_in[6];
  const float* gamma   = (const float*)d_in[7];
  const float* beta    = (const float*)d_in[8];
  const float* kpts    = (const float*)d_in[9];
  float* x = (float*)d_out;

  char* ws = (char*)d_ws;
  _Float16* featH = (_Float16*)ws;                  // 8,388,608 B
  _Float16* owt   = (_Float16*)(ws + 8388608);      //   131,072 B
  _Float16* wt    = (_Float16*)(ws + 8519680);      //   131,072 B
  float*    stats = (float*)(ws + 8650752);         //       512 B

  k_prep<<<4352, 256, 0, stream>>>(oweight, weight, feat, owt, wt, featH, stats);
  k_fused<<<4096, 256, 0, stream>>>(query, support, nidx, featH, kpts, obias,
                                    owt, wt, x, stats);
  k_norm<<<4096, 256, 0, stream>>>(x, stats, gamma, beta);
}

// Round 5
// 290.432 us; speedup vs baseline: 1.0699x; 1.0699x over previous
//
#include <hip/hip_runtime.h>
#include <math.h>

#define NPTS 65536

using half8   = __attribute__((ext_vector_type(8))) _Float16;
using half4   = __attribute__((ext_vector_type(4))) _Float16;
using floatx4 = __attribute__((ext_vector_type(4))) float;

// ---------------------------------------------------------------------------
// k_prep: weights -> f16 [64 d][1024 kc'] with kc' = c*16 + k (k=15 row zero);
//         features -> f16 table featH[N][64]. Block 0 also zeroes stats.
// ---------------------------------------------------------------------------
__global__ __launch_bounds__(256) void k_prep(
    const float* __restrict__ ow, const float* __restrict__ w,
    const float* __restrict__ feat,
    _Float16* __restrict__ owt, _Float16* __restrict__ wt,
    _Float16* __restrict__ featH, float* __restrict__ stats)
{
  int b = blockIdx.x;
  if (b < 256) {                       // 256*256 == 65536 == 64*1024
    int i = b * 256 + threadIdx.x;
    int d = i >> 10, kc = i & 1023, c = kc >> 4, k = kc & 15;
    owt[i] = (k < 15 && d < 60) ? (_Float16)ow[(k * 64 + c) * 60 + d] : (_Float16)0.f;
    wt[i]  = (k < 15) ? (_Float16)w[(k * 64 + c) * 64 + d] : (_Float16)0.f;
    if (b == 0 && threadIdx.x < 128) stats[threadIdx.x] = 0.f;
  } else {                             // 4096*256 == 1048576 == N*64/4
    int j = (b - 256) * 256 + threadIdx.x;
    float4 f = ((const float4*)feat)[j];
    half4 h = {(_Float16)f.x, (_Float16)f.y, (_Float16)f.z, (_Float16)f.w};
    ((half4*)featH)[j] = h;
  }
}

// ---------------------------------------------------------------------------
// Fused deformable KPConv. 16 pts/block, 4 waves x 4 pts.
// Consolidation round: round-0 half-K structure (205us, 84 VGPR, no spill,
// 3 blocks/CU) + only the independently-proven deltas:
//  * rank-2 neighbors (32,33) via chained MFMA (a2/b2), modulation folded
//    into A rows (lane row == kernel point)  [rounds 3/4, correct]
//  * np4 float4 staging + dot-form influence  [round 4]
//  * per-block fx2s table -> load_g/transpose_g are clean 2-iter/128-task
//    loops, 32 staging VGPRs instead of 48   [round 2, functional]
//  * packed-f16 hold for ct2/3 (16 regs vs 32)
//  * batch stats fused into GEMM1 epilogue; stats zeroed in k_prep
// Half-K GEMM (4 sync pairs): quarter-K's 8 sync pairs cost +13us at the
// same 3-block residency (round 0 vs 3). (256,4) is a proven spill trap
// (rounds 1/4: VGPR forced to 64, 100-350MB scratch traffic).
// LDS 50752 B -> 3 blocks/CU.
// ---------------------------------------------------------------------------
__global__ __launch_bounds__(256, 3) void k_fused(
    const float* __restrict__ query, const float* __restrict__ support,
    const int* __restrict__ nidx, const _Float16* __restrict__ featH,
    const float* __restrict__ kpts, const float* __restrict__ obias,
    const _Float16* __restrict__ owt, const _Float16* __restrict__ wt,
    float* __restrict__ outx, float* __restrict__ stats)
{
  __shared__ float4                 np4[16][34];     // (dx,dy,dz,|np|^2) 8704B
  __shared__ unsigned short         sidx[16][34];    // 1088B
  __shared__ __align__(16) _Float16 fT[4][64 * 32];  // per-wave transpose 16384B
  __shared__ unsigned int           fx2s[16][64];    // (f32,f33) per pt,c 4096B
  __shared__ __align__(16) _Float16 wfh[16 * 520];   // half-K A-panel 16640B
  __shared__ float                  dk[16][60];      // def_kp(45)+mod(15) 3840B

  const int tid  = threadIdx.x;
  const int wave = tid >> 6, lane = tid & 63;
  const int quad = lane >> 4, mm = lane & 15;
  const int base = blockIdx.x * 16;
  _Float16* fTw = fT[wave];
  unsigned int* fTw32 = (unsigned int*)fTw;
  const floatx4 fz = {0.f, 0.f, 0.f, 0.f};
  const int me = (mm < 15) ? mm : 14;   // row 15 of conv A is discarded

  // ---- stage neighbor displacements (+|np|^2) + indices ----
  for (int s = tid; s < 544; s += 256) {
    int pt = s / 34, a = s - pt * 34;
    int n = base + pt;
    int id = nidx[n * 34 + a];
    float dx = support[id * 3 + 0] - query[n * 3 + 0];
    float dy = support[id * 3 + 1] - query[n * 3 + 1];
    float dz = support[id * 3 + 2] - query[n * 3 + 2];
    float4 q = {dx, dy, dz, dx * dx + dy * dy + dz * dz};
    np4[pt][a] = q;
    sidx[pt][a] = (unsigned short)id;
  }
  __syncthreads();

  // ---- rank-2 neighbor (rows 32,33) features -> fx2s[pt][c], once/block ----
  if (tid < 128) {
    int pt = tid >> 3, ch = tid & 7;
    int i0 = (int)sidx[pt][32], i1 = (int)sidx[pt][33];
    uint4 g0 = *(const uint4*)(featH + i0 * 64 + ch * 8);
    uint4 g1 = *(const uint4*)(featH + i1 * 64 + ch * 8);
    const uint* p0 = (const uint*)&g0;
    const uint* p1 = (const uint*)&g1;
    #pragma unroll
    for (int cc = 0; cc < 8; ++cc) {
      uint v = __builtin_amdgcn_perm(p1[cc >> 1], p0[cc >> 1],
                                     (cc & 1) ? 0x07060302u : 0x05040100u);
      fx2s[pt][ch * 8 + cc] = v;
    }
  }
  __syncthreads();

  // ---- gather loads: 16 row-pairs x 8 chunks = 128 tasks, 2 full iters ----
  auto load_g = [&](int pl, uint4* g0, uint4* g1) {
    #pragma unroll
    for (int it = 0; it < 2; ++it) {
      int task = it * 64 + lane;
      int rp = task >> 3, ch = task & 7;
      int i0 = (int)sidx[pl][2 * rp], i1 = (int)sidx[pl][2 * rp + 1];
      g0[it] = *(const uint4*)(featH + i0 * 64 + ch * 8);
      g1[it] = *(const uint4*)(featH + i1 * 64 + ch * 8);
    }
  };
  // ---- transpose staged regs -> fTw ----
  auto transpose_g = [&](const uint4* g0, const uint4* g1) {
    #pragma unroll
    for (int it = 0; it < 2; ++it) {
      int task = it * 64 + lane;
      int rp = task >> 3, ch = task & 7;
      int chunk = rp >> 2, o = rp & 3;
      const uint* p0 = (const uint*)&g0[it];
      const uint* p1 = (const uint*)&g1[it];
      #pragma unroll
      for (int cc = 0; cc < 8; ++cc) {
        int c  = ch * 8 + cc;
        int pc = chunk ^ ((ch ^ cc) & 3);
        uint v = __builtin_amdgcn_perm(p1[cc >> 1], p0[cc >> 1],
                                       (cc & 1) ? 0x07060302u : 0x05040100u);
        fTw32[c * 16 + pc * 4 + o] = v;
      }
    }
  };

  // ---- one conv point: 4x (MFMA nbr0..31 + chained rank-2 MFMA nbr32,33).
  //      modulation pre-folded into A rows (lane row == kernel point).
  //      writes ct0/ct1 to wfh, returns ct2/ct3 packed in hq2[2] ----
  auto conv_point = [&](int pl, float kx, float ky, float kz, float modme,
                        half4* hq2) {
    float hk = kx * kx + ky * ky + kz * kz;
    half8 a0;
    #pragma unroll
    for (int j = 0; j < 8; ++j) {
      int a = quad * 8 + j;
      float4 q = np4[pl][a];
      float dt = q.x * kx + q.y * ky + q.z * kz;
      float d2 = fmaxf(q.w + hk - 2.f * dt, 0.f);
      a0[j] = (_Float16)(fmaxf(1.f - 2.f * sqrtf(d2), 0.f) * modme);
    }
    // rank-2 rows: virtual k'=0,1 supplied only by quad-0 lanes (row = mm)
    float4 q = np4[pl][32];
    float dt = q.x * kx + q.y * ky + q.z * kz;
    float w32 = fmaxf(1.f - 2.f * sqrtf(fmaxf(q.w + hk - 2.f * dt, 0.f)), 0.f) * modme;
    q = np4[pl][33];
    dt = q.x * kx + q.y * ky + q.z * kz;
    float w33 = fmaxf(1.f - 2.f * sqrtf(fmaxf(q.w + hk - 2.f * dt, 0.f)), 0.f) * modme;
    half8 a2 = {};
    a2[0] = (_Float16)((quad == 0) ? w32 : 0.f);
    a2[1] = (_Float16)((quad == 0) ? w33 : 0.f);
    #pragma unroll
    for (int ct = 0; ct < 4; ++ct) {
      int c  = ct * 16 + mm;
      int pc = quad ^ (((c >> 3) ^ c) & 3);
      half8 b = *(const half8*)(fTw + c * 32 + pc * 8);
      floatx4 acc = __builtin_amdgcn_mfma_f32_16x16x32_f16(a0, b, fz, 0, 0, 0);
      uint fp = fx2s[pl][c];
      half8 b2 = {};
      b2[0] = __builtin_bit_cast(_Float16, (unsigned short)(fp & 0xffffu));
      b2[1] = __builtin_bit_cast(_Float16, (unsigned short)(fp >> 16));
      acc = __builtin_amdgcn_mfma_f32_16x16x32_f16(a2, b2, acc, 0, 0, 0);
      half4 h = {(_Float16)acc[0], (_Float16)acc[1],
                 (_Float16)acc[2], (_Float16)acc[3]};
      if (ct < 2) *(half4*)(wfh + pl * 520 + (ct * 16 + mm) * 16 + quad * 4) = h;
      else        hq2[ct - 2] = h;
    }
  };

  // ---- write held ct2/3 (packed) into wfh (phase B slots) ----
  auto write_hold = [&](const half4 (*hq)[2]) {
    #pragma unroll
    for (int pp = 0; pp < 4; ++pp) {
      #pragma unroll
      for (int t = 0; t < 2; ++t)
        *(half4*)(wfh + (wave * 4 + pp) * 520 + (t * 16 + mm) * 16 + quad * 4) =
            hq[pp][t];
    }
  };

  // ---- half-K GEMM: 16 k-steps vs bmat rows [64][1024], offset 0 or 512 ----
  auto gemm_half = [&](const _Float16* bmat, int koff, floatx4& A, floatx4& B) {
    const _Float16* brow = bmat + (wave * 16 + mm) * 1024 + koff;
    const _Float16* arow = wfh + mm * 520;
    #pragma unroll
    for (int k2 = 0; k2 < 16; ++k2) {
      half8 af = *(const half8*)(arow + k2 * 32 + quad * 8);
      half8 bf = *(const half8*)(brow + k2 * 32 + quad * 8);
      if (k2 & 1) B = __builtin_amdgcn_mfma_f32_16x16x32_f16(af, bf, B, 0, 0, 0);
      else        A = __builtin_amdgcn_mfma_f32_16x16x32_f16(af, bf, A, 0, 0, 0);
    }
  };

  uint4 G0[2][2], G1[2][2];
  half4 hq[4][2];           // deferred ct2/3, packed f16 (16 VGPRs)
  const float k0x = kpts[me * 3 + 0], k0y = kpts[me * 3 + 1], k0z = kpts[me * 3 + 2];

  // ================= conv0 (rigid kernel points) =================
  {
    load_g(wave * 4, G0[0], G1[0]);
    #pragma unroll
    for (int pp = 0; pp < 4; ++pp) {
      int pl = wave * 4 + pp;
      if (pp < 3) load_g(pl + 1, G0[(pp + 1) & 1], G1[(pp + 1) & 1]);
      transpose_g(G0[pp & 1], G1[pp & 1]);
      conv_point(pl, k0x, k0y, k0z, 1.f, hq[pp]);
    }
  }
  load_g(wave * 4, G0[0], G1[0]);   // prefetch conv1 p0 under GEMM0
  __syncthreads();

  // ================= GEMM0 (2 half-K phases) -> def_kp + modulations =========
  {
    floatx4 A = fz, B = fz;
    gemm_half(owt, 0, A, B);
    __syncthreads();
    write_hold(hq);
    __syncthreads();
    gemm_half(owt, 512, A, B);
    int d = wave * 16 + mm;
    float bv = (d < 60) ? obias[d] : 0.f;
    float kv = (d < 45) ? kpts[d] : 0.f;
    #pragma unroll
    for (int r = 0; r < 4; ++r) {
      int pt = quad * 4 + r;
      float v = A[r] + B[r] + bv;
      if (d < 60)
        dk[pt][d] = (d < 45) ? (kv + 0.5f * v)            // def_kp = kp + f0*EXTENT
                             : (2.f / (1.f + expf(-v)));  // modulation
    }
  }
  __syncthreads();   // dk ready; GEMM0 wfh reads done

  // ================= conv1 (deformed kernel points) =================
  #pragma unroll
  for (int pp = 0; pp < 4; ++pp) {
    int pl = wave * 4 + pp;
    if (pp < 3) load_g(pl + 1, G0[(pp + 1) & 1], G1[(pp + 1) & 1]);
    float kx = dk[pl][me * 3 + 0], ky = dk[pl][me * 3 + 1], kz = dk[pl][me * 3 + 2];
    float modme = dk[pl][45 + me];
    transpose_g(G0[pp & 1], G1[pp & 1]);
    conv_point(pl, kx, ky, kz, modme, hq[pp]);
  }
  __syncthreads();

  // ================= GEMM1 (2 half-K phases) -> x + fused batch stats ========
  {
    floatx4 A = fz, B = fz;
    gemm_half(wt, 0, A, B);
    __syncthreads();
    write_hold(hq);
    __syncthreads();
    gemm_half(wt, 512, A, B);
    int d = wave * 16 + mm;
    float s1 = 0.f, s2 = 0.f;
    #pragma unroll
    for (int r = 0; r < 4; ++r) {
      float v = A[r] + B[r];
      outx[(base + quad * 4 + r) * 64 + d] = v;
      s1 += v; s2 += v * v;
    }
    s1 += __shfl_xor(s1, 16); s2 += __shfl_xor(s2, 16);
    s1 += __shfl_xor(s1, 32); s2 += __shfl_xor(s2, 32);
    if (lane < 16) {
      atomicAdd(&stats[d], s1);
      atomicAdd(&stats[64 + d], s2);
    }
  }
}

// ---------------------------------------------------------------------------
// BN (batch stats, biased var, eps=1e-6) + LeakyReLU(0.1), in-place
// ---------------------------------------------------------------------------
__global__ __launch_bounds__(256) void k_norm(
    float* __restrict__ x, const float* __restrict__ stats,
    const float* __restrict__ gamma, const float* __restrict__ beta)
{
  const int i = blockIdx.x * 256 + threadIdx.x;
  float4 v = ((float4*)x)[i];
  const int c0 = (i * 4) & 63;
  float o[4] = {v.x, v.y, v.z, v.w};
  #pragma unroll
  for (int j = 0; j < 4; ++j) {
    int c = c0 + j;
    float mean = stats[c] * (1.f / NPTS);
    float var  = stats[64 + c] * (1.f / NPTS) - mean * mean;
    float s = rsqrtf(var + 1e-6f) * gamma[c];
    float y = (o[j] - mean) * s + beta[c];
    o[j] = (y >= 0.f) ? y : 0.1f * y;
  }
  float4 rv = {o[0], o[1], o[2], o[3]};
  ((float4*)x)[i] = rv;
}

// ---------------------------------------------------------------------------
extern "C" void kernel_launch(void* const* d_in, const int* in_sizes, int n_in,
                              void* d_out, int out_size, void* d_ws, size_t ws_size,
                              hipStream_t stream)
{
  const float* query   = (const float*)d_in[0];
  const float* support = (const float*)d_in[1];
  const int*   nidx    = (const int*)d_in[2];
  const float* feat    = (const float*)d_in[3];
  const float* weight  = (const float*)d_in[4];
  const float* oweight = (const float*)d_in[5];
  const float* obias   = (const float*)d_in[6];
  const float* gamma   = (const float*)d_in[7];
  const float* beta    = (const float*)d_in[8];
  const float* kpts    = (const float*)d_in[9];
  float* x = (float*)d_out;

  char* ws = (char*)d_ws;
  _Float16* featH = (_Float16*)ws;                  // 8,388,608 B
  _Float16* owt   = (_Float16*)(ws + 8388608);      //   131,072 B
  _Float16* wt    = (_Float16*)(ws + 8519680);      //   131,072 B
  float*    stats = (float*)(ws + 8650752);         //       512 B

  k_prep<<<4352, 256, 0, stream>>>(oweight, weight, feat, owt, wt, featH, stats);
  k_fused<<<4096, 256, 0, stream>>>(query, support, nidx, featH, kpts, obias,
                                    owt, wt, x, stats);
  k_norm<<<4096, 256, 0, stream>>>(x, stats, gamma, beta);
}

// Round 8
// 287.471 us; speedup vs baseline: 1.0809x; 1.0103x over previous
//
#include <hip/hip_runtime.h>
#include <math.h>

#define NPTS 65536

using half8   = __attribute__((ext_vector_type(8))) _Float16;
using half4   = __attribute__((ext_vector_type(4))) _Float16;
using floatx4 = __attribute__((ext_vector_type(4))) float;

// ---------------------------------------------------------------------------
// k_prep: weights -> f16 [64 d][1024 kc'] with kc' = c*16 + k (k=15 row zero);
//         features -> f16 table featH[N][64]. Block 0 also zeroes stats.
// ---------------------------------------------------------------------------
__global__ __launch_bounds__(256) void k_prep(
    const float* __restrict__ ow, const float* __restrict__ w,
    const float* __restrict__ feat,
    _Float16* __restrict__ owt, _Float16* __restrict__ wt,
    _Float16* __restrict__ featH, float* __restrict__ stats)
{
  int b = blockIdx.x;
  if (b < 256) {                       // 256*256 == 65536 == 64*1024
    int i = b * 256 + threadIdx.x;
    int d = i >> 10, kc = i & 1023, c = kc >> 4, k = kc & 15;
    owt[i] = (k < 15 && d < 60) ? (_Float16)ow[(k * 64 + c) * 60 + d] : (_Float16)0.f;
    wt[i]  = (k < 15) ? (_Float16)w[(k * 64 + c) * 64 + d] : (_Float16)0.f;
    if (b == 0 && threadIdx.x < 128) stats[threadIdx.x] = 0.f;
  } else {                             // 4096*256 == 1048576 == N*64/4
    int j = (b - 256) * 256 + threadIdx.x;
    float4 f = ((const float4*)feat)[j];
    half4 h = {(_Float16)f.x, (_Float16)f.y, (_Float16)f.z, (_Float16)f.w};
    ((half4*)featH)[j] = h;
  }
}

// ---------------------------------------------------------------------------
// Fused deformable KPConv. 16 pts/block, 4 waves x 4 pts.
// All components bit-exact from PASSING rounds; only two structural deltas:
//  * single 16-reg gather buffer (G0[2],G1[2]); next point's load issued
//    right after transpose frees G -- conv_point (~500cy MFMA+VALU) covers
//    the L2 gather latency. (was 32 regs double-buffered)
//  * (256,4): with arch regs ~52-60 + ~32 acc the unified total fits the
//    128-reg/wave budget, so 4 waves/EU without spills (rounds 1/4 spilled
//    because those designs needed >128 total).
// LDS 40384 B (np split-f32 6528 + sidx 1088 + fT 16384 + fx2s 4096 +
// wfh quarter-K 8448 + dk f32 3840) -> 4 blocks/CU (4 x 40448 <= 160K).
// Proven parts: 128-task load/transpose (r5), fx2s table (r5), quarter-K
// conv_point + chained rank-2 MFMA + modme fold + packed hq (r3/4),
// quarter gemm_q (r3), subtract-form influence (r0), fused stats (r3-5).
// Tripwire: WRITE_SIZE ~18MB else spilling -> revert to (256,3) next.
// ---------------------------------------------------------------------------
__global__ __launch_bounds__(256, 4) void k_fused(
    const float* __restrict__ query, const float* __restrict__ support,
    const int* __restrict__ nidx, const _Float16* __restrict__ featH,
    const float* __restrict__ kpts, const float* __restrict__ obias,
    const _Float16* __restrict__ owt, const _Float16* __restrict__ wt,
    float* __restrict__ outx, float* __restrict__ stats)
{
  __shared__ float                  npx[16][34], npy[16][34], npz[16][34]; // 6528B
  __shared__ unsigned short         sidx[16][34];    // 1088B
  __shared__ __align__(16) _Float16 fT[4][64 * 32];  // per-wave transpose 16384B
  __shared__ unsigned int           fx2s[16][64];    // (f32,f33) per pt,c 4096B
  __shared__ __align__(16) _Float16 wfh[16 * 264];   // quarter-K A-panel 8448B
  __shared__ float                  dk[16][60];      // def_kp(45)+mod(15) 3840B

  const int tid  = threadIdx.x;
  const int wave = tid >> 6, lane = tid & 63;
  const int quad = lane >> 4, mm = lane & 15;
  const int base = blockIdx.x * 16;
  _Float16* fTw = fT[wave];
  unsigned int* fTw32 = (unsigned int*)fTw;
  const floatx4 fz = {0.f, 0.f, 0.f, 0.f};
  const int me = (mm < 15) ? mm : 14;   // row 15 of conv A is discarded

  // ---- stage neighbor displacements + indices ----
  for (int s = tid; s < 544; s += 256) {
    int pt = s / 34, a = s - pt * 34;
    int n = base + pt;
    int id = nidx[n * 34 + a];
    npx[pt][a] = support[id * 3 + 0] - query[n * 3 + 0];
    npy[pt][a] = support[id * 3 + 1] - query[n * 3 + 1];
    npz[pt][a] = support[id * 3 + 2] - query[n * 3 + 2];
    sidx[pt][a] = (unsigned short)id;
  }
  __syncthreads();

  // ---- rank-2 neighbor (rows 32,33) features -> fx2s[pt][c], once/block ----
  if (tid < 128) {
    int pt = tid >> 3, ch = tid & 7;
    int i0 = (int)sidx[pt][32], i1 = (int)sidx[pt][33];
    uint4 g0 = *(const uint4*)(featH + i0 * 64 + ch * 8);
    uint4 g1 = *(const uint4*)(featH + i1 * 64 + ch * 8);
    const uint* p0 = (const uint*)&g0;
    const uint* p1 = (const uint*)&g1;
    #pragma unroll
    for (int cc = 0; cc < 8; ++cc) {
      uint v = __builtin_amdgcn_perm(p1[cc >> 1], p0[cc >> 1],
                                     (cc & 1) ? 0x07060302u : 0x05040100u);
      fx2s[pt][ch * 8 + cc] = v;
    }
  }
  __syncthreads();

  // ---- gather loads: 16 row-pairs x 8 chunks = 128 tasks, 2 full iters ----
  auto load_g = [&](int pl, uint4* g0, uint4* g1) {
    #pragma unroll
    for (int it = 0; it < 2; ++it) {
      int task = it * 64 + lane;
      int rp = task >> 3, ch = task & 7;
      int i0 = (int)sidx[pl][2 * rp], i1 = (int)sidx[pl][2 * rp + 1];
      g0[it] = *(const uint4*)(featH + i0 * 64 + ch * 8);
      g1[it] = *(const uint4*)(featH + i1 * 64 + ch * 8);
    }
  };
  // ---- transpose staged regs -> fTw ----
  auto transpose_g = [&](const uint4* g0, const uint4* g1) {
    #pragma unroll
    for (int it = 0; it < 2; ++it) {
      int task = it * 64 + lane;
      int rp = task >> 3, ch = task & 7;
      int chunk = rp >> 2, o = rp & 3;
      const uint* p0 = (const uint*)&g0[it];
      const uint* p1 = (const uint*)&g1[it];
      #pragma unroll
      for (int cc = 0; cc < 8; ++cc) {
        int c  = ch * 8 + cc;
        int pc = chunk ^ ((ch ^ cc) & 3);
        uint v = __builtin_amdgcn_perm(p1[cc >> 1], p0[cc >> 1],
                                       (cc & 1) ? 0x07060302u : 0x05040100u);
        fTw32[c * 16 + pc * 4 + o] = v;
      }
    }
  };

  // ---- one conv point: 4x (MFMA nbr0..31 + chained rank-2 MFMA nbr32,33).
  //      modulation pre-folded into A rows (lane row == kernel point).
  //      writes ct0 quarter to wfh, returns ct1..3 packed in hq3[3] ----
  auto conv_point = [&](int pl, float kx, float ky, float kz, float modme,
                        half4* hq3) {
    half8 a0;
    #pragma unroll
    for (int j = 0; j < 8; ++j) {
      int a = quad * 8 + j;
      float dx = npx[pl][a] - kx, dy = npy[pl][a] - ky, dz = npz[pl][a] - kz;
      float wv = 1.f - 2.f * sqrtf(dx * dx + dy * dy + dz * dz);
      a0[j] = (_Float16)(fmaxf(wv, 0.f) * modme);
    }
    // rank-2 rows: virtual k'=0,1 supplied only by quad-0 lanes (row = mm)
    float dx = npx[pl][32] - kx, dy = npy[pl][32] - ky, dz = npz[pl][32] - kz;
    float w32 = fmaxf(1.f - 2.f * sqrtf(dx * dx + dy * dy + dz * dz), 0.f) * modme;
    dx = npx[pl][33] - kx; dy = npy[pl][33] - ky; dz = npz[pl][33] - kz;
    float w33 = fmaxf(1.f - 2.f * sqrtf(dx * dx + dy * dy + dz * dz), 0.f) * modme;
    half8 a2 = {};
    a2[0] = (_Float16)((quad == 0) ? w32 : 0.f);
    a2[1] = (_Float16)((quad == 0) ? w33 : 0.f);
    #pragma unroll
    for (int ct = 0; ct < 4; ++ct) {
      int c  = ct * 16 + mm;
      int pc = quad ^ (((c >> 3) ^ c) & 3);
      half8 b = *(const half8*)(fTw + c * 32 + pc * 8);
      floatx4 acc = __builtin_amdgcn_mfma_f32_16x16x32_f16(a0, b, fz, 0, 0, 0);
      uint fp = fx2s[pl][c];
      half8 b2 = {};
      b2[0] = __builtin_bit_cast(_Float16, (unsigned short)(fp & 0xffffu));
      b2[1] = __builtin_bit_cast(_Float16, (unsigned short)(fp >> 16));
      acc = __builtin_amdgcn_mfma_f32_16x16x32_f16(a2, b2, acc, 0, 0, 0);
      half4 h = {(_Float16)acc[0], (_Float16)acc[1],
                 (_Float16)acc[2], (_Float16)acc[3]};
      if (ct == 0) *(half4*)(wfh + pl * 264 + mm * 16 + quad * 4) = h;
      else         hq3[ct - 1] = h;
    }
  };

  // ---- write one held quarter (ct = idx+1) into wfh ----
  auto write_hold = [&](const half4 (*hq)[3], int idx) {
    #pragma unroll
    for (int pp = 0; pp < 4; ++pp)
      *(half4*)(wfh + (wave * 4 + pp) * 264 + mm * 16 + quad * 4) = hq[pp][idx];
  };

  // ---- quarter-K GEMM: 8 k-steps vs bmat rows [64][1024], quarter p ----
  auto gemm_q = [&](const _Float16* bmat, int p, floatx4& A, floatx4& B) {
    const _Float16* brow = bmat + (wave * 16 + mm) * 1024 + p * 256;
    const _Float16* arow = wfh + mm * 264;
    #pragma unroll
    for (int k2 = 0; k2 < 8; ++k2) {
      half8 af = *(const half8*)(arow + k2 * 32 + quad * 8);
      half8 bf = *(const half8*)(brow + k2 * 32 + quad * 8);
      if (k2 & 1) B = __builtin_amdgcn_mfma_f32_16x16x32_f16(af, bf, B, 0, 0, 0);
      else        A = __builtin_amdgcn_mfma_f32_16x16x32_f16(af, bf, A, 0, 0, 0);
    }
  };

  uint4 G0[2], G1[2];       // single gather buffer (16 VGPRs)
  half4 hq[4][3];           // deferred quarters, packed f16 (12 VGPRs)
  const float k0x = kpts[me * 3 + 0], k0y = kpts[me * 3 + 1], k0z = kpts[me * 3 + 2];

  // ================= conv0 (rigid kernel points) =================
  {
    load_g(wave * 4, G0, G1);
    #pragma unroll
    for (int pp = 0; pp < 4; ++pp) {
      int pl = wave * 4 + pp;
      transpose_g(G0, G1);
      if (pp < 3) load_g(pl + 1, G0, G1);   // issue next gather; conv covers it
      conv_point(pl, k0x, k0y, k0z, 1.f, hq[pp]);
    }
  }
  load_g(wave * 4, G0, G1);   // prefetch conv1 p0 under GEMM0
  __syncthreads();

  // ================= GEMM0 (4 quarter phases) -> def_kp + modulations ========
  {
    floatx4 A = fz, B = fz;
    gemm_q(owt, 0, A, B);
    __syncthreads(); write_hold(hq, 0); __syncthreads();
    gemm_q(owt, 1, A, B);
    __syncthreads(); write_hold(hq, 1); __syncthreads();
    gemm_q(owt, 2, A, B);
    __syncthreads(); write_hold(hq, 2); __syncthreads();
    gemm_q(owt, 3, A, B);
    int d = wave * 16 + mm;
    float bv = (d < 60) ? obias[d] : 0.f;
    float kv = (d < 45) ? kpts[d] : 0.f;
    #pragma unroll
    for (int r = 0; r < 4; ++r) {
      int pt = quad * 4 + r;
      float v = A[r] + B[r] + bv;
      if (d < 60)
        dk[pt][d] = (d < 45) ? (kv + 0.5f * v)            // def_kp = kp + f0*EXTENT
                             : (2.f / (1.f + expf(-v)));  // modulation
    }
  }
  __syncthreads();   // dk ready; GEMM0 wfh reads done

  // ================= conv1 (deformed kernel points) =================
  #pragma unroll
  for (int pp = 0; pp < 4; ++pp) {
    int pl = wave * 4 + pp;
    float kx = dk[pl][me * 3 + 0], ky = dk[pl][me * 3 + 1], kz = dk[pl][me * 3 + 2];
    float modme = dk[pl][45 + me];
    transpose_g(G0, G1);
    if (pp < 3) load_g(pl + 1, G0, G1);
    conv_point(pl, kx, ky, kz, modme, hq[pp]);
  }
  __syncthreads();

  // ================= GEMM1 (4 quarter phases) -> x + fused batch stats =======
  {
    floatx4 A = fz, B = fz;
    gemm_q(wt, 0, A, B);
    __syncthreads(); write_hold(hq, 0); __syncthreads();
    gemm_q(wt, 1, A, B);
    __syncthreads(); write_hold(hq, 1); __syncthreads();
    gemm_q(wt, 2, A, B);
    __syncthreads(); write_hold(hq, 2); __syncthreads();
    gemm_q(wt, 3, A, B);
    int d = wave * 16 + mm;
    float s1 = 0.f, s2 = 0.f;
    #pragma unroll
    for (int r = 0; r < 4; ++r) {
      float v = A[r] + B[r];
      outx[(base + quad * 4 + r) * 64 + d] = v;
      s1 += v; s2 += v * v;
    }
    s1 += __shfl_xor(s1, 16); s2 += __shfl_xor(s2, 16);
    s1 += __shfl_xor(s1, 32); s2 += __shfl_xor(s2, 32);
    if (lane < 16) {
      atomicAdd(&stats[d], s1);
      atomicAdd(&stats[64 + d], s2);
    }
  }
}

// ---------------------------------------------------------------------------
// BN (batch stats, biased var, eps=1e-6) + LeakyReLU(0.1), in-place
// ---------------------------------------------------------------------------
__global__ __launch_bounds__(256) void k_norm(
    float* __restrict__ x, const float* __restrict__ stats,
    const float* __restrict__ gamma, const float* __restrict__ beta)
{
  const int i = blockIdx.x * 256 + threadIdx.x;
  float4 v = ((float4*)x)[i];
  const int c0 = (i * 4) & 63;
  float o[4] = {v.x, v.y, v.z, v.w};
  #pragma unroll
  for (int j = 0; j < 4; ++j) {
    int c = c0 + j;
    float mean = stats[c] * (1.f / NPTS);
    float var  = stats[64 + c] * (1.f / NPTS) - mean * mean;
    float s = rsqrtf(var + 1e-6f) * gamma[c];
    float y = (o[j] - mean) * s + beta[c];
    o[j] = (y >= 0.f) ? y : 0.1f * y;
  }
  float4 rv = {o[0], o[1], o[2], o[3]};
  ((float4*)x)[i] = rv;
}

// ---------------------------------------------------------------------------
extern "C" void kernel_launch(void* const* d_in, const int* in_sizes, int n_in,
                              void* d_out, int out_size, void* d_ws, size_t ws_size,
                              hipStream_t stream)
{
  const float* query   = (const float*)d_in[0];
  const float* support = (const float*)d_in[1];
  const int*   nidx    = (const int*)d_in[2];
  const float* feat    = (const float*)d_in[3];
  const float* weight  = (const float*)d_in[4];
  const float* oweight = (const float*)d_in[5];
  const float* obias   = (const float*)d_in[6];
  const float* gamma   = (const float*)d_in[7];
  const float* beta    = (const float*)d_in[8];
  const float* kpts    = (const float*)d_in[9];
  float* x = (float*)d_out;

  char* ws = (char*)d_ws;
  _Float16* featH = (_Float16*)ws;                  // 8,388,608 B
  _Float16* owt   = (_Float16*)(ws + 8388608);      //   131,072 B
  _Float16* wt    = (_Float16*)(ws + 8519680);      //   131,072 B
  float*    stats = (float*)(ws + 8650752);         //       512 B

  k_prep<<<4352, 256, 0, stream>>>(oweight, weight, feat, owt, wt, featH, stats);
  k_fused<<<4096, 256, 0, stream>>>(query, support, nidx, featH, kpts, obias,
                                    owt, wt, x, stats);
  k_norm<<<4096, 256, 0, stream>>>(x, stats, gamma, beta);
}

// Round 11
// 284.834 us; speedup vs baseline: 1.0909x; 1.0093x over previous
//
#include <hip/hip_runtime.h>
#include <math.h>

#define NPTS 65536

using half8   = __attribute__((ext_vector_type(8))) _Float16;
using half4   = __attribute__((ext_vector_type(4))) _Float16;
using floatx4 = __attribute__((ext_vector_type(4))) float;

// ---------------------------------------------------------------------------
// k_prep: weights -> f16 [64 d][1024 kc'] with kc' = c*16 + k (k=15 row zero);
//         features -> f16 table featH[N][64]. Block 0 also zeroes stats.
// Weight transform is LDS-tiled so BOTH global sides are coalesced (the old
// version read stride-240B / wrote stride-2KB scattered -> ~64 lines/wave).
// 32 blocks per matrix: block = (kc-chunk of 256) x (d-chunk of 8).
// ---------------------------------------------------------------------------
__global__ __launch_bounds__(256) void k_prep(
    const float* __restrict__ ow, const float* __restrict__ w,
    const float* __restrict__ feat,
    _Float16* __restrict__ owt, _Float16* __restrict__ wt,
    _Float16* __restrict__ featH, float* __restrict__ stats)
{
  int b = blockIdx.x;
  if (b < 64) {                        // 2 matrices x 32 tiles
    __shared__ float tile[256][9];     // pad 9: conflict-free both passes
    int mat = b >> 5, bb = b & 31;
    int kcb = bb & 3, db = bb >> 2;
    int t = threadIdx.x;
    int kc = kcb * 256 + t;
    int c = kc >> 4, k = kc & 15;
    const float* src = mat ? w : ow;
    int dmax = mat ? 64 : 60;
    #pragma unroll
    for (int di = 0; di < 8; ++di) {   // coalesced-ish reads (32B runs)
      int d = db * 8 + di;
      float v = 0.f;
      if (k < 15 && d < dmax) v = src[(k * 64 + c) * dmax + d];
      tile[t][di] = v;
    }
    __syncthreads();
    _Float16* dst = mat ? wt : owt;
    #pragma unroll
    for (int di = 0; di < 8; ++di) {   // fully coalesced writes (128B/wave)
      int d = db * 8 + di;
      dst[d * 1024 + kcb * 256 + t] = (_Float16)tile[t][di];
    }
    if (b == 0 && t < 128) stats[t] = 0.f;
  } else {                             // 4096*256 == 1048576 == N*64/4
    int j = (b - 64) * 256 + threadIdx.x;
    float4 f = ((const float4*)feat)[j];
    half4 h = {(_Float16)f.x, (_Float16)f.y, (_Float16)f.z, (_Float16)f.w};
    ((half4*)featH)[j] = h;
  }
}

// ---------------------------------------------------------------------------
// Fused deformable KPConv. 16 pts/block, 4 waves x 4 pts. Round-8 base
// (passing, 203us k_fused) + ONE bit-exact delta:
//  * transpose-store channel swizzle fc = swap(bit0,bit3)(c): store bank =
//    16*(fc&1)+4*pc+o; old fc&1 = cc&1 was FIXED per store instruction ->
//    16 banks -> 4-way conflict on all 128 b32 stores/point. New fc&1 = ch&1
//    varies across lanes -> 32 banks -> 2-way (free, m136). Conv reads row
//    ct*16+mm which now holds true channel c = ct*16+swap03(mm); fx2s and
//    wfh positions are keyed by that c. Pure relabeling, bit-exact.
// (re-derived: GEMM A-reads at stride 264 are already bank-uniform; the
// r9 "268 pad" was pointless and is dropped.)
// LDS 40448 B -> 4 blocks/CU, (256,4), VGPR 64, no spills (r8-verified).
// ---------------------------------------------------------------------------
__global__ __launch_bounds__(256, 4) void k_fused(
    const float* __restrict__ query, const float* __restrict__ support,
    const int* __restrict__ nidx, const _Float16* __restrict__ featH,
    const float* __restrict__ kpts, const float* __restrict__ obias,
    const _Float16* __restrict__ owt, const _Float16* __restrict__ wt,
    float* __restrict__ outx, float* __restrict__ stats)
{
  __shared__ float                  npx[16][34], npy[16][34], npz[16][34]; // 6528B
  __shared__ unsigned short         sidx[16][34];    // 1088B
  __shared__ __align__(16) _Float16 fT[4][64 * 32];  // per-wave transpose 16384B
  __shared__ unsigned int           fx2s[16][64];    // (f32,f33) per pt,c 4096B
  __shared__ __align__(16) _Float16 wfh[16 * 264];   // quarter-K A-panel 8448B
  __shared__ float                  dk[16][60];      // def_kp(45)+mod(15) 3840B

  const int tid  = threadIdx.x;
  const int wave = tid >> 6, lane = tid & 63;
  const int quad = lane >> 4, mm = lane & 15;
  const int base = blockIdx.x * 16;
  _Float16* fTw = fT[wave];
  unsigned int* fTw32 = (unsigned int*)fTw;
  const floatx4 fz = {0.f, 0.f, 0.f, 0.f};
  const int me = (mm < 15) ? mm : 14;   // row 15 of conv A is discarded
  // swap bits 0<->3 of mm: channel this lane computes within each quarter
  const int mmw = (mm & 6) | ((mm & 1) << 3) | ((mm >> 3) & 1);

  // ---- stage neighbor displacements + indices ----
  for (int s = tid; s < 544; s += 256) {
    int pt = s / 34, a = s - pt * 34;
    int n = base + pt;
    int id = nidx[n * 34 + a];
    npx[pt][a] = support[id * 3 + 0] - query[n * 3 + 0];
    npy[pt][a] = support[id * 3 + 1] - query[n * 3 + 1];
    npz[pt][a] = support[id * 3 + 2] - query[n * 3 + 2];
    sidx[pt][a] = (unsigned short)id;
  }
  __syncthreads();

  // ---- rank-2 neighbor (rows 32,33) features -> fx2s[pt][c], once/block ----
  if (tid < 128) {
    int pt = tid >> 3, ch = tid & 7;
    int i0 = (int)sidx[pt][32], i1 = (int)sidx[pt][33];
    uint4 g0 = *(const uint4*)(featH + i0 * 64 + ch * 8);
    uint4 g1 = *(const uint4*)(featH + i1 * 64 + ch * 8);
    const uint* p0 = (const uint*)&g0;
    const uint* p1 = (const uint*)&g1;
    #pragma unroll
    for (int cc = 0; cc < 8; ++cc) {
      uint v = __builtin_amdgcn_perm(p1[cc >> 1], p0[cc >> 1],
                                     (cc & 1) ? 0x07060302u : 0x05040100u);
      fx2s[pt][ch * 8 + cc] = v;
    }
  }
  __syncthreads();

  // ---- gather loads: 16 row-pairs x 8 chunks = 128 tasks, 2 full iters ----
  auto load_g = [&](int pl, uint4* g0, uint4* g1) {
    #pragma unroll
    for (int it = 0; it < 2; ++it) {
      int task = it * 64 + lane;
      int rp = task >> 3, ch = task & 7;
      int i0 = (int)sidx[pl][2 * rp], i1 = (int)sidx[pl][2 * rp + 1];
      g0[it] = *(const uint4*)(featH + i0 * 64 + ch * 8);
      g1[it] = *(const uint4*)(featH + i1 * 64 + ch * 8);
    }
  };
  // ---- transpose staged regs -> fTw at swizzled row fc = swap03(c) ----
  auto transpose_g = [&](const uint4* g0, const uint4* g1) {
    #pragma unroll
    for (int it = 0; it < 2; ++it) {
      int task = it * 64 + lane;
      int rp = task >> 3, ch = task & 7;
      int chunk = rp >> 2, o = rp & 3;
      const uint* p0 = (const uint*)&g0[it];
      const uint* p1 = (const uint*)&g1[it];
      #pragma unroll
      for (int cc = 0; cc < 8; ++cc) {
        int c  = ch * 8 + cc;
        int fc = (c & 0x36) | ((c & 1) << 3) | ((c >> 3) & 1);
        int pc = chunk ^ ((ch ^ cc) & 3);     // salt keyed by TRUE c
        uint v = __builtin_amdgcn_perm(p1[cc >> 1], p0[cc >> 1],
                                       (cc & 1) ? 0x07060302u : 0x05040100u);
        fTw32[fc * 16 + pc * 4 + o] = v;
      }
    }
  };

  // ---- one conv point: 4x (MFMA nbr0..31 + chained rank-2 MFMA nbr32,33).
  //      lane's channel within quarter ct is c = ct*16+mmw (stored at row
  //      ct*16+mm). modulation pre-folded into A rows (lane row == kp).
  //      writes ct0 quarter to wfh, returns ct1..3 packed in hq3[3] ----
  auto conv_point = [&](int pl, float kx, float ky, float kz, float modme,
                        half4* hq3) {
    half8 a0;
    #pragma unroll
    for (int j = 0; j < 8; ++j) {
      int a = quad * 8 + j;
      float dx = npx[pl][a] - kx, dy = npy[pl][a] - ky, dz = npz[pl][a] - kz;
      float wv = 1.f - 2.f * sqrtf(dx * dx + dy * dy + dz * dz);
      a0[j] = (_Float16)(fmaxf(wv, 0.f) * modme);
    }
    // rank-2 rows: virtual k'=0,1 supplied only by quad-0 lanes (row = mm)
    float dx = npx[pl][32] - kx, dy = npy[pl][32] - ky, dz = npz[pl][32] - kz;
    float w32 = fmaxf(1.f - 2.f * sqrtf(dx * dx + dy * dy + dz * dz), 0.f) * modme;
    dx = npx[pl][33] - kx; dy = npy[pl][33] - ky; dz = npz[pl][33] - kz;
    float w33 = fmaxf(1.f - 2.f * sqrtf(dx * dx + dy * dy + dz * dz), 0.f) * modme;
    half8 a2 = {};
    a2[0] = (_Float16)((quad == 0) ? w32 : 0.f);
    a2[1] = (_Float16)((quad == 0) ? w33 : 0.f);
    #pragma unroll
    for (int ct = 0; ct < 4; ++ct) {
      int c  = ct * 16 + mmw;                 // true channel
      int pc = quad ^ (((c >> 3) ^ c) & 3);
      half8 b = *(const half8*)(fTw + (ct * 16 + mm) * 32 + pc * 8);
      floatx4 acc = __builtin_amdgcn_mfma_f32_16x16x32_f16(a0, b, fz, 0, 0, 0);
      uint fp = fx2s[pl][c];
      half8 b2 = {};
      b2[0] = __builtin_bit_cast(_Float16, (unsigned short)(fp & 0xffffu));
      b2[1] = __builtin_bit_cast(_Float16, (unsigned short)(fp >> 16));
      acc = __builtin_amdgcn_mfma_f32_16x16x32_f16(a2, b2, acc, 0, 0, 0);
      half4 h = {(_Float16)acc[0], (_Float16)acc[1],
                 (_Float16)acc[2], (_Float16)acc[3]};
      if (ct == 0) *(half4*)(wfh + pl * 264 + mmw * 16 + quad * 4) = h;
      else         hq3[ct - 1] = h;
    }
  };

  // ---- write one held quarter (ct = idx+1) into wfh (row = mmw) ----
  auto write_hold = [&](const half4 (*hq)[3], int idx) {
    #pragma unroll
    for (int pp = 0; pp < 4; ++pp)
      *(half4*)(wfh + (wave * 4 + pp) * 264 + mmw * 16 + quad * 4) = hq[pp][idx];
  };

  // ---- quarter-K GEMM: 8 k-steps vs bmat rows [64][1024], quarter p ----
  auto gemm_q = [&](const _Float16* bmat, int p, floatx4& A, floatx4& B) {
    const _Float16* brow = bmat + (wave * 16 + mm) * 1024 + p * 256;
    const _Float16* arow = wfh + mm * 264;
    #pragma unroll
    for (int k2 = 0; k2 < 8; ++k2) {
      half8 af = *(const half8*)(arow + k2 * 32 + quad * 8);
      half8 bf = *(const half8*)(brow + k2 * 32 + quad * 8);
      if (k2 & 1) B = __builtin_amdgcn_mfma_f32_16x16x32_f16(af, bf, B, 0, 0, 0);
      else        A = __builtin_amdgcn_mfma_f32_16x16x32_f16(af, bf, A, 0, 0, 0);
    }
  };

  uint4 G0[2], G1[2];       // single gather buffer (16 VGPRs)
  half4 hq[4][3];           // deferred quarters, packed f16 (12 VGPRs)
  const float k0x = kpts[me * 3 + 0], k0y = kpts[me * 3 + 1], k0z = kpts[me * 3 + 2];

  // ================= conv0 (rigid kernel points) =================
  {
    load_g(wave * 4, G0, G1);
    #pragma unroll
    for (int pp = 0; pp < 4; ++pp) {
      int pl = wave * 4 + pp;
      transpose_g(G0, G1);
      if (pp < 3) load_g(pl + 1, G0, G1);   // issue next gather; conv covers it
      conv_point(pl, k0x, k0y, k0z, 1.f, hq[pp]);
    }
  }
  load_g(wave * 4, G0, G1);   // prefetch conv1 p0 under GEMM0
  __syncthreads();

  // ================= GEMM0 (4 quarter phases) -> def_kp + modulations ========
  {
    floatx4 A = fz, B = fz;
    gemm_q(owt, 0, A, B);
    __syncthreads(); write_hold(hq, 0); __syncthreads();
    gemm_q(owt, 1, A, B);
    __syncthreads(); write_hold(hq, 1); __syncthreads();
    gemm_q(owt, 2, A, B);
    __syncthreads(); write_hold(hq, 2); __syncthreads();
    gemm_q(owt, 3, A, B);
    int d = wave * 16 + mm;
    float bv = (d < 60) ? obias[d] : 0.f;
    float kv = (d < 45) ? kpts[d] : 0.f;
    #pragma unroll
    for (int r = 0; r < 4; ++r) {
      int pt = quad * 4 + r;
      float v = A[r] + B[r] + bv;
      if (d < 60)
        dk[pt][d] = (d < 45) ? (kv + 0.5f * v)            // def_kp = kp + f0*EXTENT
                             : (2.f / (1.f + expf(-v)));  // modulation
    }
  }
  __syncthreads();   // dk ready; GEMM0 wfh reads done

  // ================= conv1 (deformed kernel points) =================
  #pragma unroll
  for (int pp = 0; pp < 4; ++pp) {
    int pl = wave * 4 + pp;
    float kx = dk[pl][me * 3 + 0], ky = dk[pl][me * 3 + 1], kz = dk[pl][me * 3 + 2];
    float modme = dk[pl][45 + me];
    transpose_g(G0, G1);
    if (pp < 3) load_g(pl + 1, G0, G1);
    conv_point(pl, kx, ky, kz, modme, hq[pp]);
  }
  __syncthreads();

  // ================= GEMM1 (4 quarter phases) -> x + fused batch stats =======
  {
    floatx4 A = fz, B = fz;
    gemm_q(wt, 0, A, B);
    __syncthreads(); write_hold(hq, 0); __syncthreads();
    gemm_q(wt, 1, A, B);
    __syncthreads(); write_hold(hq, 1); __syncthreads();
    gemm_q(wt, 2, A, B);
    __syncthreads(); write_hold(hq, 2); __syncthreads();
    gemm_q(wt, 3, A, B);
    int d = wave * 16 + mm;
    float s1 = 0.f, s2 = 0.f;
    #pragma unroll
    for (int r = 0; r < 4; ++r) {
      float v = A[r] + B[r];
      outx[(base + quad * 4 + r) * 64 + d] = v;
      s1 += v; s2 += v * v;
    }
    s1 += __shfl_xor(s1, 16); s2 += __shfl_xor(s2, 16);
    s1 += __shfl_xor(s1, 32); s2 += __shfl_xor(s2, 32);
    if (lane < 16) {
      atomicAdd(&stats[d], s1);
      atomicAdd(&stats[64 + d], s2);
    }
  }
}

// ---------------------------------------------------------------------------
// BN (batch stats, biased var, eps=1e-6) + LeakyReLU(0.1), in-place
// ---------------------------------------------------------------------------
__global__ __launch_bounds__(256) void k_norm(
    float* __restrict__ x, const float* __restrict__ stats,
    const float* __restrict__ gamma, const float* __restrict__ beta)
{
  const int i = blockIdx.x * 256 + threadIdx.x;
  float4 v = ((float4*)x)[i];
  const int c0 = (i * 4) & 63;
  float o[4] = {v.x, v.y, v.z, v.w};
  #pragma unroll
  for (int j = 0; j < 4; ++j) {
    int c = c0 + j;
    float mean = stats[c] * (1.f / NPTS);
    float var  = stats[64 + c] * (1.f / NPTS) - mean * mean;
    float s = rsqrtf(var + 1e-6f) * gamma[c];
    float y = (o[j] - mean) * s + beta[c];
    o[j] = (y >= 0.f) ? y : 0.1f * y;
  }
  float4 rv = {o[0], o[1], o[2], o[3]};
  ((float4*)x)[i] = rv;
}

// ---------------------------------------------------------------------------
extern "C" void kernel_launch(void* const* d_in, const int* in_sizes, int n_in,
                              void* d_out, int out_size, void* d_ws, size_t ws_size,
                              hipStream_t stream)
{
  const float* query   = (const float*)d_in[0];
  const float* support = (const float*)d_in[1];
  const int*   nidx    = (const int*)d_in[2];
  const float* feat    = (const float*)d_in[3];
  const float* weight  = (const float*)d_in[4];
  const float* oweight = (const float*)d_in[5];
  const float* obias   = (const float*)d_in[6];
  const float* gamma   = (const float*)d_in[7];
  const float* beta    = (const float*)d_in[8];
  const float* kpts    = (const float*)d_in[9];
  float* x = (float*)d_out;

  char* ws = (char*)d_ws;
  _Float16* featH = (_Float16*)ws;                  // 8,388,608 B
  _Float16* owt   = (_Float16*)(ws + 8388608);      //   131,072 B
  _Float16* wt    = (_Float16*)(ws + 8519680);      //   131,072 B
  float*    stats = (float*)(ws + 8650752);         //       512 B

  k_prep<<<4160, 256, 0, stream>>>(oweight, weight, feat, owt, wt, featH, stats);
  k_fused<<<4096, 256, 0, stream>>>(query, support, nidx, featH, kpts, obias,
                                    owt, wt, x, stats);
  k_norm<<<4096, 256, 0, stream>>>(x, stats, gamma, beta);
}

// Round 12
// 256.966 us; speedup vs baseline: 1.2092x; 1.1084x over previous
//
#include <hip/hip_runtime.h>
#include <math.h>

#define NPTS 65536

using half8   = __attribute__((ext_vector_type(8))) _Float16;
using half4   = __attribute__((ext_vector_type(4))) _Float16;
using floatx4 = __attribute__((ext_vector_type(4))) float;

// ---------------------------------------------------------------------------
// k_prep: weights -> f16 in GEMM-COALESCED layout:
//   element (d, kc) at [((w*4+p)*8 + k2)*512 + mm*32 + (kc&31)]
//   where d = w*16+mm, kc = p*256 + k2*32 + (kc&31).
//   A wave (fixed w,p,k2) then reads halfs [X, X+512) = one contiguous 1KB
//   line per k-step (old d-major layout scattered each wave-load into 16
//   64B segments 2KB apart -> 2x L2 request amplification in the GEMMs).
// features -> f16 table featH[N][64]. Block 0 also zeroes stats.
// ---------------------------------------------------------------------------
__global__ __launch_bounds__(256) void k_prep(
    const float* __restrict__ ow, const float* __restrict__ w,
    const float* __restrict__ feat,
    _Float16* __restrict__ owt, _Float16* __restrict__ wt,
    _Float16* __restrict__ featH, float* __restrict__ stats)
{
  int b = blockIdx.x;
  if (b < 64) {                        // 2 matrices x (4 kc-chunks x 8 d-chunks)
    __shared__ float tile[256][9];     // pad 9: conflict-free both passes
    int mat = b >> 5, bb = b & 31;
    int kcb = bb & 3, db = bb >> 2;    // kcb == p (quarter), db = d-chunk of 8
    int t = threadIdx.x;
    int kc = kcb * 256 + t;
    int c = kc >> 4, k = kc & 15;
    const float* src = mat ? w : ow;
    int dmax = mat ? 64 : 60;
    #pragma unroll
    for (int di = 0; di < 8; ++di) {
      int d = db * 8 + di;
      float v = 0.f;
      if (k < 15 && d < dmax) v = src[(k * 64 + c) * dmax + d];
      tile[t][di] = v;
    }
    __syncthreads();
    _Float16* dst = mat ? wt : owt;
    int k2 = t >> 5, lo = t & 31;      // k-step, within-32 offset
    #pragma unroll
    for (int di = 0; di < 8; ++di) {   // 64B-run writes
      int d = db * 8 + di;
      int wv = d >> 4, mm = d & 15;
      dst[((wv * 4 + kcb) * 8 + k2) * 512 + mm * 32 + lo] = (_Float16)tile[t][di];
    }
    if (b == 0 && t < 128) stats[t] = 0.f;
  } else {                             // 4096*256 == 1048576 == N*64/4
    int j = (b - 64) * 256 + threadIdx.x;
    float4 f = ((const float4*)feat)[j];
    half4 h = {(_Float16)f.x, (_Float16)f.y, (_Float16)f.z, (_Float16)f.w};
    ((half4*)featH)[j] = h;
  }
}

// ---------------------------------------------------------------------------
// Fused deformable KPConv. 16 pts/block, 4 waves x 4 pts. Round-11 base
// (passing, 201us) + ONE bit-exact delta: gemm_q reads the new coalesced
// B layout -- each k-step is one contiguous 1KB wave-load from L2 instead
// of 16 scattered 64B segments. All conv/sync/layout structure frozen.
// (Bank-conflict thread CLOSED: counter pinned at 1.69e7 across 4 layouts,
// uncorrelated with time -- b128 multi-beat accounting, not a lever.)
// LDS 40448 B -> 4 blocks/CU, (256,4), VGPR 64, no spills (r11-verified).
// ---------------------------------------------------------------------------
__global__ __launch_bounds__(256, 4) void k_fused(
    const float* __restrict__ query, const float* __restrict__ support,
    const int* __restrict__ nidx, const _Float16* __restrict__ featH,
    const float* __restrict__ kpts, const float* __restrict__ obias,
    const _Float16* __restrict__ owt, const _Float16* __restrict__ wt,
    float* __restrict__ outx, float* __restrict__ stats)
{
  __shared__ float                  npx[16][34], npy[16][34], npz[16][34]; // 6528B
  __shared__ unsigned short         sidx[16][34];    // 1088B
  __shared__ __align__(16) _Float16 fT[4][64 * 32];  // per-wave transpose 16384B
  __shared__ unsigned int           fx2s[16][64];    // (f32,f33) per pt,c 4096B
  __shared__ __align__(16) _Float16 wfh[16 * 264];   // quarter-K A-panel 8448B
  __shared__ float                  dk[16][60];      // def_kp(45)+mod(15) 3840B

  const int tid  = threadIdx.x;
  const int wave = tid >> 6, lane = tid & 63;
  const int quad = lane >> 4, mm = lane & 15;
  const int base = blockIdx.x * 16;
  _Float16* fTw = fT[wave];
  unsigned int* fTw32 = (unsigned int*)fTw;
  const floatx4 fz = {0.f, 0.f, 0.f, 0.f};
  const int me = (mm < 15) ? mm : 14;   // row 15 of conv A is discarded
  // swap bits 0<->3 of mm: channel this lane computes within each quarter
  const int mmw = (mm & 6) | ((mm & 1) << 3) | ((mm >> 3) & 1);

  // ---- stage neighbor displacements + indices ----
  for (int s = tid; s < 544; s += 256) {
    int pt = s / 34, a = s - pt * 34;
    int n = base + pt;
    int id = nidx[n * 34 + a];
    npx[pt][a] = support[id * 3 + 0] - query[n * 3 + 0];
    npy[pt][a] = support[id * 3 + 1] - query[n * 3 + 1];
    npz[pt][a] = support[id * 3 + 2] - query[n * 3 + 2];
    sidx[pt][a] = (unsigned short)id;
  }
  __syncthreads();

  // ---- rank-2 neighbor (rows 32,33) features -> fx2s[pt][c], once/block ----
  if (tid < 128) {
    int pt = tid >> 3, ch = tid & 7;
    int i0 = (int)sidx[pt][32], i1 = (int)sidx[pt][33];
    uint4 g0 = *(const uint4*)(featH + i0 * 64 + ch * 8);
    uint4 g1 = *(const uint4*)(featH + i1 * 64 + ch * 8);
    const uint* p0 = (const uint*)&g0;
    const uint* p1 = (const uint*)&g1;
    #pragma unroll
    for (int cc = 0; cc < 8; ++cc) {
      uint v = __builtin_amdgcn_perm(p1[cc >> 1], p0[cc >> 1],
                                     (cc & 1) ? 0x07060302u : 0x05040100u);
      fx2s[pt][ch * 8 + cc] = v;
    }
  }
  __syncthreads();

  // ---- gather loads: 16 row-pairs x 8 chunks = 128 tasks, 2 full iters ----
  auto load_g = [&](int pl, uint4* g0, uint4* g1) {
    #pragma unroll
    for (int it = 0; it < 2; ++it) {
      int task = it * 64 + lane;
      int rp = task >> 3, ch = task & 7;
      int i0 = (int)sidx[pl][2 * rp], i1 = (int)sidx[pl][2 * rp + 1];
      g0[it] = *(const uint4*)(featH + i0 * 64 + ch * 8);
      g1[it] = *(const uint4*)(featH + i1 * 64 + ch * 8);
    }
  };
  // ---- transpose staged regs -> fTw at swizzled row fc = swap03(c) ----
  auto transpose_g = [&](const uint4* g0, const uint4* g1) {
    #pragma unroll
    for (int it = 0; it < 2; ++it) {
      int task = it * 64 + lane;
      int rp = task >> 3, ch = task & 7;
      int chunk = rp >> 2, o = rp & 3;
      const uint* p0 = (const uint*)&g0[it];
      const uint* p1 = (const uint*)&g1[it];
      #pragma unroll
      for (int cc = 0; cc < 8; ++cc) {
        int c  = ch * 8 + cc;
        int fc = (c & 0x36) | ((c & 1) << 3) | ((c >> 3) & 1);
        int pc = chunk ^ ((ch ^ cc) & 3);     // salt keyed by TRUE c
        uint v = __builtin_amdgcn_perm(p1[cc >> 1], p0[cc >> 1],
                                       (cc & 1) ? 0x07060302u : 0x05040100u);
        fTw32[fc * 16 + pc * 4 + o] = v;
      }
    }
  };

  // ---- one conv point: 4x (MFMA nbr0..31 + chained rank-2 MFMA nbr32,33).
  //      lane's channel within quarter ct is c = ct*16+mmw (stored at row
  //      ct*16+mm). modulation pre-folded into A rows (lane row == kp).
  //      writes ct0 quarter to wfh, returns ct1..3 packed in hq3[3] ----
  auto conv_point = [&](int pl, float kx, float ky, float kz, float modme,
                        half4* hq3) {
    half8 a0;
    #pragma unroll
    for (int j = 0; j < 8; ++j) {
      int a = quad * 8 + j;
      float dx = npx[pl][a] - kx, dy = npy[pl][a] - ky, dz = npz[pl][a] - kz;
      float wv = 1.f - 2.f * sqrtf(dx * dx + dy * dy + dz * dz);
      a0[j] = (_Float16)(fmaxf(wv, 0.f) * modme);
    }
    // rank-2 rows: virtual k'=0,1 supplied only by quad-0 lanes (row = mm)
    float dx = npx[pl][32] - kx, dy = npy[pl][32] - ky, dz = npz[pl][32] - kz;
    float w32 = fmaxf(1.f - 2.f * sqrtf(dx * dx + dy * dy + dz * dz), 0.f) * modme;
    dx = npx[pl][33] - kx; dy = npy[pl][33] - ky; dz = npz[pl][33] - kz;
    float w33 = fmaxf(1.f - 2.f * sqrtf(dx * dx + dy * dy + dz * dz), 0.f) * modme;
    half8 a2 = {};
    a2[0] = (_Float16)((quad == 0) ? w32 : 0.f);
    a2[1] = (_Float16)((quad == 0) ? w33 : 0.f);
    #pragma unroll
    for (int ct = 0; ct < 4; ++ct) {
      int c  = ct * 16 + mmw;                 // true channel
      int pc = quad ^ (((c >> 3) ^ c) & 3);
      half8 b = *(const half8*)(fTw + (ct * 16 + mm) * 32 + pc * 8);
      floatx4 acc = __builtin_amdgcn_mfma_f32_16x16x32_f16(a0, b, fz, 0, 0, 0);
      uint fp = fx2s[pl][c];
      half8 b2 = {};
      b2[0] = __builtin_bit_cast(_Float16, (unsigned short)(fp & 0xffffu));
      b2[1] = __builtin_bit_cast(_Float16, (unsigned short)(fp >> 16));
      acc = __builtin_amdgcn_mfma_f32_16x16x32_f16(a2, b2, acc, 0, 0, 0);
      half4 h = {(_Float16)acc[0], (_Float16)acc[1],
                 (_Float16)acc[2], (_Float16)acc[3]};
      if (ct == 0) *(half4*)(wfh + pl * 264 + mmw * 16 + quad * 4) = h;
      else         hq3[ct - 1] = h;
    }
  };

  // ---- write one held quarter (ct = idx+1) into wfh (row = mmw) ----
  auto write_hold = [&](const half4 (*hq)[3], int idx) {
    #pragma unroll
    for (int pp = 0; pp < 4; ++pp)
      *(half4*)(wfh + (wave * 4 + pp) * 264 + mmw * 16 + quad * 4) = hq[pp][idx];
  };

  // ---- quarter-K GEMM: 8 k-steps; B layout coalesced: one contiguous 1KB
  //      wave-load per k-step at [((wave*4+p)*8+k2)*512 + mm*32 + quad*8] ----
  auto gemm_q = [&](const _Float16* bmat, int p, floatx4& A, floatx4& B) {
    const _Float16* brow = bmat + ((wave * 4 + p) * 8) * 512 + mm * 32 + quad * 8;
    const _Float16* arow = wfh + mm * 264;
    #pragma unroll
    for (int k2 = 0; k2 < 8; ++k2) {
      half8 af = *(const half8*)(arow + k2 * 32 + quad * 8);
      half8 bf = *(const half8*)(brow + k2 * 512);
      if (k2 & 1) B = __builtin_amdgcn_mfma_f32_16x16x32_f16(af, bf, B, 0, 0, 0);
      else        A = __builtin_amdgcn_mfma_f32_16x16x32_f16(af, bf, A, 0, 0, 0);
    }
  };

  uint4 G0[2], G1[2];       // single gather buffer (16 VGPRs)
  half4 hq[4][3];           // deferred quarters, packed f16 (12 VGPRs)
  const float k0x = kpts[me * 3 + 0], k0y = kpts[me * 3 + 1], k0z = kpts[me * 3 + 2];

  // ================= conv0 (rigid kernel points) =================
  {
    load_g(wave * 4, G0, G1);
    #pragma unroll
    for (int pp = 0; pp < 4; ++pp) {
      int pl = wave * 4 + pp;
      transpose_g(G0, G1);
      if (pp < 3) load_g(pl + 1, G0, G1);   // issue next gather; conv covers it
      conv_point(pl, k0x, k0y, k0z, 1.f, hq[pp]);
    }
  }
  load_g(wave * 4, G0, G1);   // prefetch conv1 p0 under GEMM0
  __syncthreads();

  // ================= GEMM0 (4 quarter phases) -> def_kp + modulations ========
  {
    floatx4 A = fz, B = fz;
    gemm_q(owt, 0, A, B);
    __syncthreads(); write_hold(hq, 0); __syncthreads();
    gemm_q(owt, 1, A, B);
    __syncthreads(); write_hold(hq, 1); __syncthreads();
    gemm_q(owt, 2, A, B);
    __syncthreads(); write_hold(hq, 2); __syncthreads();
    gemm_q(owt, 3, A, B);
    int d = wave * 16 + mm;
    float bv = (d < 60) ? obias[d] : 0.f;
    float kv = (d < 45) ? kpts[d] : 0.f;
    #pragma unroll
    for (int r = 0; r < 4; ++r) {
      int pt = quad * 4 + r;
      float v = A[r] + B[r] + bv;
      if (d < 60)
        dk[pt][d] = (d < 45) ? (kv + 0.5f * v)            // def_kp = kp + f0*EXTENT
                             : (2.f / (1.f + expf(-v)));  // modulation
    }
  }
  __syncthreads();   // dk ready; GEMM0 wfh reads done

  // ================= conv1 (deformed kernel points) =================
  #pragma unroll
  for (int pp = 0; pp < 4; ++pp) {
    int pl = wave * 4 + pp;
    float kx = dk[pl][me * 3 + 0], ky = dk[pl][me * 3 + 1], kz = dk[pl][me * 3 + 2];
    float modme = dk[pl][45 + me];
    transpose_g(G0, G1);
    if (pp < 3) load_g(pl + 1, G0, G1);
    conv_point(pl, kx, ky, kz, modme, hq[pp]);
  }
  __syncthreads();

  // ================= GEMM1 (4 quarter phases) -> x + fused batch stats =======
  {
    floatx4 A = fz, B = fz;
    gemm_q(wt, 0, A, B);
    __syncthreads(); write_hold(hq, 0); __syncthreads();
    gemm_q(wt, 1, A, B);
    __syncthreads(); write_hold(hq, 1); __syncthreads();
    gemm_q(wt, 2, A, B);
    __syncthreads(); write_hold(hq, 2); __syncthreads();
    gemm_q(wt, 3, A, B);
    int d = wave * 16 + mm;
    float s1 = 0.f, s2 = 0.f;
    #pragma unroll
    for (int r = 0; r < 4; ++r) {
      float v = A[r] + B[r];
      outx[(base + quad * 4 + r) * 64 + d] = v;
      s1 += v; s2 += v * v;
    }
    s1 += __shfl_xor(s1, 16); s2 += __shfl_xor(s2, 16);
    s1 += __shfl_xor(s1, 32); s2 += __shfl_xor(s2, 32);
    if (lane < 16) {
      atomicAdd(&stats[d], s1);
      atomicAdd(&stats[64 + d], s2);
    }
  }
}

// ---------------------------------------------------------------------------
// BN (batch stats, biased var, eps=1e-6) + LeakyReLU(0.1), in-place
// ---------------------------------------------------------------------------
__global__ __launch_bounds__(256) void k_norm(
    float* __restrict__ x, const float* __restrict__ stats,
    const float* __restrict__ gamma, const float* __restrict__ beta)
{
  const int i = blockIdx.x * 256 + threadIdx.x;
  float4 v = ((float4*)x)[i];
  const int c0 = (i * 4) & 63;
  float o[4] = {v.x, v.y, v.z, v.w};
  #pragma unroll
  for (int j = 0; j < 4; ++j) {
    int c = c0 + j;
    float mean = stats[c] * (1.f / NPTS);
    float var  = stats[64 + c] * (1.f / NPTS) - mean * mean;
    float s = rsqrtf(var + 1e-6f) * gamma[c];
    float y = (o[j] - mean) * s + beta[c];
    o[j] = (y >= 0.f) ? y : 0.1f * y;
  }
  float4 rv = {o[0], o[1], o[2], o[3]};
  ((float4*)x)[i] = rv;
}

// ---------------------------------------------------------------------------
extern "C" void kernel_launch(void* const* d_in, const int* in_sizes, int n_in,
                              void* d_out, int out_size, void* d_ws, size_t ws_size,
                              hipStream_t stream)
{
  const float* query   = (const float*)d_in[0];
  const float* support = (const float*)d_in[1];
  const int*   nidx    = (const int*)d_in[2];
  const float* feat    = (const float*)d_in[3];
  const float* weight  = (const float*)d_in[4];
  const float* oweight = (const float*)d_in[5];
  const float* obias   = (const float*)d_in[6];
  const float* gamma   = (const float*)d_in[7];
  const float* beta    = (const float*)d_in[8];
  const float* kpts    = (const float*)d_in[9];
  float* x = (float*)d_out;

  char* ws = (char*)d_ws;
  _Float16* featH = (_Float16*)ws;                  // 8,388,608 B
  _Float16* owt   = (_Float16*)(ws + 8388608);      //   131,072 B
  _Float16* wt    = (_Float16*)(ws + 8519680);      //   131,072 B
  float*    stats = (float*)(ws + 8650752);         //       512 B

  k_prep<<<4160, 256, 0, stream>>>(oweight, weight, feat, owt, wt, featH, stats);
  k_fused<<<4096, 256, 0, stream>>>(query, support, nidx, featH, kpts, obias,
                                    owt, wt, x, stats);
  k_norm<<<4096, 256, 0, stream>>>(x, stats, gamma, beta);
}

// Round 13
// 254.028 us; speedup vs baseline: 1.2232x; 1.0116x over previous
//
#include <hip/hip_runtime.h>
#include <math.h>

#define NPTS 65536

using half8   = __attribute__((ext_vector_type(8))) _Float16;
using half4   = __attribute__((ext_vector_type(4))) _Float16;
using floatx4 = __attribute__((ext_vector_type(4))) float;

// ---------------------------------------------------------------------------
// k_prep: weights -> f16 in GEMM-COALESCED layout:
//   element (d, kc) at [((w*4+p)*8 + k2)*512 + mm*32 + (kc&31)]
//   where d = w*16+mm, kc = p*256 + k2*32 + (kc&31).
//   A wave (fixed w,p,k2) reads one contiguous 1KB line per k-step (r12 win:
//   k_fused 201->173us vs the old d-major scatter).
// features -> f16 table featH[N][64]. Block 0 also zeroes stats.
// ---------------------------------------------------------------------------
__global__ __launch_bounds__(256) void k_prep(
    const float* __restrict__ ow, const float* __restrict__ w,
    const float* __restrict__ feat,
    _Float16* __restrict__ owt, _Float16* __restrict__ wt,
    _Float16* __restrict__ featH, float* __restrict__ stats)
{
  int b = blockIdx.x;
  if (b < 64) {                        // 2 matrices x (4 kc-chunks x 8 d-chunks)
    __shared__ float tile[256][9];     // pad 9: conflict-free both passes
    int mat = b >> 5, bb = b & 31;
    int kcb = bb & 3, db = bb >> 2;    // kcb == p (quarter), db = d-chunk of 8
    int t = threadIdx.x;
    int kc = kcb * 256 + t;
    int c = kc >> 4, k = kc & 15;
    const float* src = mat ? w : ow;
    int dmax = mat ? 64 : 60;
    #pragma unroll
    for (int di = 0; di < 8; ++di) {
      int d = db * 8 + di;
      float v = 0.f;
      if (k < 15 && d < dmax) v = src[(k * 64 + c) * dmax + d];
      tile[t][di] = v;
    }
    __syncthreads();
    _Float16* dst = mat ? wt : owt;
    int k2 = t >> 5, lo = t & 31;      // k-step, within-32 offset
    #pragma unroll
    for (int di = 0; di < 8; ++di) {   // 64B-run writes
      int d = db * 8 + di;
      int wv = d >> 4, mm = d & 15;
      dst[((wv * 4 + kcb) * 8 + k2) * 512 + mm * 32 + lo] = (_Float16)tile[t][di];
    }
    if (b == 0 && t < 128) stats[t] = 0.f;
  } else {                             // 4096*256 == 1048576 == N*64/4
    int j = (b - 64) * 256 + threadIdx.x;
    float4 f = ((const float4*)feat)[j];
    half4 h = {(_Float16)f.x, (_Float16)f.y, (_Float16)f.z, (_Float16)f.w};
    ((half4*)featH)[j] = h;
  }
}

// ---------------------------------------------------------------------------
// Fused deformable KPConv. 16 pts/block, 4 waves x 4 pts. Round-12 base
// (passing, 173us steady) + two deltas targeting the dominant VALU bucket:
//  * dot-form influence w/ float4 np staging (r4-proven): per neighbor one
//    ds_read_b128 + 4 VALU (d2 = |np|^2+|kp|^2-2 np.kp) instead of
//    3 ds_read_b32 + 6 VALU. LDS +2176B paid by dk->f16 (-1920B):
//    total 40640 <= 40960, still 4 blocks/CU.
//  * s_setprio(1) around the GEMM MFMA bursts (T5): blocks on a CU are
//    independently phased -> scheduler can favor the MFMA-issuing wave.
// Frozen: coalesced-B GEMM (r12), transpose swizzle fc=swap03(c) (r11),
// chained rank-2 MFMA + modme fold, quarter-K phasing, fused stats, (256,4).
// Closed threads: bank conflicts (counter pinned 1.69e7 across 4 layouts,
// uncorrelated with time); tr_read/global_load_lds path (2 correctness
// failures, unverifiable semantics).
// ---------------------------------------------------------------------------
__global__ __launch_bounds__(256, 4) void k_fused(
    const float* __restrict__ query, const float* __restrict__ support,
    const int* __restrict__ nidx, const _Float16* __restrict__ featH,
    const float* __restrict__ kpts, const float* __restrict__ obias,
    const _Float16* __restrict__ owt, const _Float16* __restrict__ wt,
    float* __restrict__ outx, float* __restrict__ stats)
{
  __shared__ float4                 np4[16][34];     // (dx,dy,dz,|np|^2) 8704B
  __shared__ unsigned short         sidx[16][34];    // 1088B
  __shared__ __align__(16) _Float16 fT[4][64 * 32];  // per-wave transpose 16384B
  __shared__ unsigned int           fx2s[16][64];    // (f32,f33) per pt,c 4096B
  __shared__ __align__(16) _Float16 wfh[16 * 264];   // quarter-K A-panel 8448B
  __shared__ _Float16               dkh[16][60];     // def_kp(45)+mod(15) 1920B

  const int tid  = threadIdx.x;
  const int wave = tid >> 6, lane = tid & 63;
  const int quad = lane >> 4, mm = lane & 15;
  const int base = blockIdx.x * 16;
  _Float16* fTw = fT[wave];
  unsigned int* fTw32 = (unsigned int*)fTw;
  const floatx4 fz = {0.f, 0.f, 0.f, 0.f};
  const int me = (mm < 15) ? mm : 14;   // row 15 of conv A is discarded
  // swap bits 0<->3 of mm: channel this lane computes within each quarter
  const int mmw = (mm & 6) | ((mm & 1) << 3) | ((mm >> 3) & 1);

  // ---- stage neighbor displacements (+|np|^2) + indices ----
  for (int s = tid; s < 544; s += 256) {
    int pt = s / 34, a = s - pt * 34;
    int n = base + pt;
    int id = nidx[n * 34 + a];
    float dx = support[id * 3 + 0] - query[n * 3 + 0];
    float dy = support[id * 3 + 1] - query[n * 3 + 1];
    float dz = support[id * 3 + 2] - query[n * 3 + 2];
    float4 q = {dx, dy, dz, dx * dx + dy * dy + dz * dz};
    np4[pt][a] = q;
    sidx[pt][a] = (unsigned short)id;
  }
  __syncthreads();

  // ---- rank-2 neighbor (rows 32,33) features -> fx2s[pt][c], once/block ----
  if (tid < 128) {
    int pt = tid >> 3, ch = tid & 7;
    int i0 = (int)sidx[pt][32], i1 = (int)sidx[pt][33];
    uint4 g0 = *(const uint4*)(featH + i0 * 64 + ch * 8);
    uint4 g1 = *(const uint4*)(featH + i1 * 64 + ch * 8);
    const uint* p0 = (const uint*)&g0;
    const uint* p1 = (const uint*)&g1;
    #pragma unroll
    for (int cc = 0; cc < 8; ++cc) {
      uint v = __builtin_amdgcn_perm(p1[cc >> 1], p0[cc >> 1],
                                     (cc & 1) ? 0x07060302u : 0x05040100u);
      fx2s[pt][ch * 8 + cc] = v;
    }
  }
  __syncthreads();

  // ---- gather loads: 16 row-pairs x 8 chunks = 128 tasks, 2 full iters ----
  auto load_g = [&](int pl, uint4* g0, uint4* g1) {
    #pragma unroll
    for (int it = 0; it < 2; ++it) {
      int task = it * 64 + lane;
      int rp = task >> 3, ch = task & 7;
      int i0 = (int)sidx[pl][2 * rp], i1 = (int)sidx[pl][2 * rp + 1];
      g0[it] = *(const uint4*)(featH + i0 * 64 + ch * 8);
      g1[it] = *(const uint4*)(featH + i1 * 64 + ch * 8);
    }
  };
  // ---- transpose staged regs -> fTw at swizzled row fc = swap03(c) ----
  auto transpose_g = [&](const uint4* g0, const uint4* g1) {
    #pragma unroll
    for (int it = 0; it < 2; ++it) {
      int task = it * 64 + lane;
      int rp = task >> 3, ch = task & 7;
      int chunk = rp >> 2, o = rp & 3;
      const uint* p0 = (const uint*)&g0[it];
      const uint* p1 = (const uint*)&g1[it];
      #pragma unroll
      for (int cc = 0; cc < 8; ++cc) {
        int c  = ch * 8 + cc;
        int fc = (c & 0x36) | ((c & 1) << 3) | ((c >> 3) & 1);
        int pc = chunk ^ ((ch ^ cc) & 3);     // salt keyed by TRUE c
        uint v = __builtin_amdgcn_perm(p1[cc >> 1], p0[cc >> 1],
                                       (cc & 1) ? 0x07060302u : 0x05040100u);
        fTw32[fc * 16 + pc * 4 + o] = v;
      }
    }
  };

  // ---- one conv point: 4x (MFMA nbr0..31 + chained rank-2 MFMA nbr32,33).
  //      dot-form influence: d2 = |np|^2 + |kp|^2 - 2 np.kp (1 b128 read).
  //      modulation pre-folded into A rows (lane row == kernel point).
  //      writes ct0 quarter to wfh, returns ct1..3 packed in hq3[3] ----
  auto conv_point = [&](int pl, float kx, float ky, float kz, float modme,
                        half4* hq3) {
    float hk = kx * kx + ky * ky + kz * kz;
    half8 a0;
    #pragma unroll
    for (int j = 0; j < 8; ++j) {
      int a = quad * 8 + j;
      float4 q = np4[pl][a];
      float dt = q.x * kx + q.y * ky + q.z * kz;
      float d2 = fmaxf(q.w + hk - 2.f * dt, 0.f);
      a0[j] = (_Float16)(fmaxf(1.f - 2.f * sqrtf(d2), 0.f) * modme);
    }
    // rank-2 rows: virtual k'=0,1 supplied only by quad-0 lanes (row = mm)
    float4 q = np4[pl][32];
    float dt = q.x * kx + q.y * ky + q.z * kz;
    float w32 = fmaxf(1.f - 2.f * sqrtf(fmaxf(q.w + hk - 2.f * dt, 0.f)), 0.f) * modme;
    q = np4[pl][33];
    dt = q.x * kx + q.y * ky + q.z * kz;
    float w33 = fmaxf(1.f - 2.f * sqrtf(fmaxf(q.w + hk - 2.f * dt, 0.f)), 0.f) * modme;
    half8 a2 = {};
    a2[0] = (_Float16)((quad == 0) ? w32 : 0.f);
    a2[1] = (_Float16)((quad == 0) ? w33 : 0.f);
    #pragma unroll
    for (int ct = 0; ct < 4; ++ct) {
      int c  = ct * 16 + mmw;                 // true channel
      int pc = quad ^ (((c >> 3) ^ c) & 3);
      half8 b = *(const half8*)(fTw + (ct * 16 + mm) * 32 + pc * 8);
      floatx4 acc = __builtin_amdgcn_mfma_f32_16x16x32_f16(a0, b, fz, 0, 0, 0);
      uint fp = fx2s[pl][c];
      half8 b2 = {};
      b2[0] = __builtin_bit_cast(_Float16, (unsigned short)(fp & 0xffffu));
      b2[1] = __builtin_bit_cast(_Float16, (unsigned short)(fp >> 16));
      acc = __builtin_amdgcn_mfma_f32_16x16x32_f16(a2, b2, acc, 0, 0, 0);
      half4 h = {(_Float16)acc[0], (_Float16)acc[1],
                 (_Float16)acc[2], (_Float16)acc[3]};
      if (ct == 0) *(half4*)(wfh + pl * 264 + mmw * 16 + quad * 4) = h;
      else         hq3[ct - 1] = h;
    }
  };

  // ---- write one held quarter (ct = idx+1) into wfh (row = mmw) ----
  auto write_hold = [&](const half4 (*hq)[3], int idx) {
    #pragma unroll
    for (int pp = 0; pp < 4; ++pp)
      *(half4*)(wfh + (wave * 4 + pp) * 264 + mmw * 16 + quad * 4) = hq[pp][idx];
  };

  // ---- quarter-K GEMM: 8 k-steps; coalesced B (1KB wave-load per k-step);
  //      setprio(1) keeps the MFMA burst fed (T5, independent-block regime) ----
  auto gemm_q = [&](const _Float16* bmat, int p, floatx4& A, floatx4& B) {
    const _Float16* brow = bmat + ((wave * 4 + p) * 8) * 512 + mm * 32 + quad * 8;
    const _Float16* arow = wfh + mm * 264;
    __builtin_amdgcn_s_setprio(1);
    #pragma unroll
    for (int k2 = 0; k2 < 8; ++k2) {
      half8 af = *(const half8*)(arow + k2 * 32 + quad * 8);
      half8 bf = *(const half8*)(brow + k2 * 512);
      if (k2 & 1) B = __builtin_amdgcn_mfma_f32_16x16x32_f16(af, bf, B, 0, 0, 0);
      else        A = __builtin_amdgcn_mfma_f32_16x16x32_f16(af, bf, A, 0, 0, 0);
    }
    __builtin_amdgcn_s_setprio(0);
  };

  uint4 G0[2], G1[2];       // single gather buffer (16 VGPRs)
  half4 hq[4][3];           // deferred quarters, packed f16 (12 VGPRs)
  const float k0x = kpts[me * 3 + 0], k0y = kpts[me * 3 + 1], k0z = kpts[me * 3 + 2];

  // ================= conv0 (rigid kernel points) =================
  {
    load_g(wave * 4, G0, G1);
    #pragma unroll
    for (int pp = 0; pp < 4; ++pp) {
      int pl = wave * 4 + pp;
      transpose_g(G0, G1);
      if (pp < 3) load_g(pl + 1, G0, G1);   // issue next gather; conv covers it
      conv_point(pl, k0x, k0y, k0z, 1.f, hq[pp]);
    }
  }
  load_g(wave * 4, G0, G1);   // prefetch conv1 p0 under GEMM0
  __syncthreads();

  // ================= GEMM0 (4 quarter phases) -> def_kp + modulations ========
  {
    floatx4 A = fz, B = fz;
    gemm_q(owt, 0, A, B);
    __syncthreads(); write_hold(hq, 0); __syncthreads();
    gemm_q(owt, 1, A, B);
    __syncthreads(); write_hold(hq, 1); __syncthreads();
    gemm_q(owt, 2, A, B);
    __syncthreads(); write_hold(hq, 2); __syncthreads();
    gemm_q(owt, 3, A, B);
    int d = wave * 16 + mm;
    float bv = (d < 60) ? obias[d] : 0.f;
    float kv = (d < 45) ? kpts[d] : 0.f;
    #pragma unroll
    for (int r = 0; r < 4; ++r) {
      int pt = quad * 4 + r;
      float v = A[r] + B[r] + bv;
      if (d < 60)
        dkh[pt][d] = (_Float16)((d < 45) ? (kv + 0.5f * v)        // kp + f0*EXTENT
                                         : (2.f / (1.f + expf(-v))));  // modulation
    }
  }
  __syncthreads();   // dkh ready; GEMM0 wfh reads done

  // ================= conv1 (deformed kernel points) =================
  #pragma unroll
  for (int pp = 0; pp < 4; ++pp) {
    int pl = wave * 4 + pp;
    float kx = (float)dkh[pl][me * 3 + 0];
    float ky = (float)dkh[pl][me * 3 + 1];
    float kz = (float)dkh[pl][me * 3 + 2];
    float modme = (float)dkh[pl][45 + me];
    transpose_g(G0, G1);
    if (pp < 3) load_g(pl + 1, G0, G1);
    conv_point(pl, kx, ky, kz, modme, hq[pp]);
  }
  __syncthreads();

  // ================= GEMM1 (4 quarter phases) -> x + fused batch stats =======
  {
    floatx4 A = fz, B = fz;
    gemm_q(wt, 0, A, B);
    __syncthreads(); write_hold(hq, 0); __syncthreads();
    gemm_q(wt, 1, A, B);
    __syncthreads(); write_hold(hq, 1); __syncthreads();
    gemm_q(wt, 2, A, B);
    __syncthreads(); write_hold(hq, 2); __syncthreads();
    gemm_q(wt, 3, A, B);
    int d = wave * 16 + mm;
    float s1 = 0.f, s2 = 0.f;
    #pragma unroll
    for (int r = 0; r < 4; ++r) {
      float v = A[r] + B[r];
      outx[(base + quad * 4 + r) * 64 + d] = v;
      s1 += v; s2 += v * v;
    }
    s1 += __shfl_xor(s1, 16); s2 += __shfl_xor(s2, 16);
    s1 += __shfl_xor(s1, 32); s2 += __shfl_xor(s2, 32);
    if (lane < 16) {
      atomicAdd(&stats[d], s1);
      atomicAdd(&stats[64 + d], s2);
    }
  }
}

// ---------------------------------------------------------------------------
// BN (batch stats, biased var, eps=1e-6) + LeakyReLU(0.1), in-place
// ---------------------------------------------------------------------------
__global__ __launch_bounds__(256) void k_norm(
    float* __restrict__ x, const float* __restrict__ stats,
    const float* __restrict__ gamma, const float* __restrict__ beta)
{
  const int i = blockIdx.x * 256 + threadIdx.x;
  float4 v = ((float4*)x)[i];
  const int c0 = (i * 4) & 63;
  float o[4] = {v.x, v.y, v.z, v.w};
  #pragma unroll
  for (int j = 0; j < 4; ++j) {
    int c = c0 + j;
    float mean = stats[c] * (1.f / NPTS);
    float var  = stats[64 + c] * (1.f / NPTS) - mean * mean;
    float s = rsqrtf(var + 1e-6f) * gamma[c];
    float y = (o[j] - mean) * s + beta[c];
    o[j] = (y >= 0.f) ? y : 0.1f * y;
  }
  float4 rv = {o[0], o[1], o[2], o[3]};
  ((float4*)x)[i] = rv;
}

// ---------------------------------------------------------------------------
extern "C" void kernel_launch(void* const* d_in, const int* in_sizes, int n_in,
                              void* d_out, int out_size, void* d_ws, size_t ws_size,
                              hipStream_t stream)
{
  const float* query   = (const float*)d_in[0];
  const float* support = (const float*)d_in[1];
  const int*   nidx    = (const int*)d_in[2];
  const float* feat    = (const float*)d_in[3];
  const float* weight  = (const float*)d_in[4];
  const float* oweight = (const float*)d_in[5];
  const float* obias   = (const float*)d_in[6];
  const float* gamma   = (const float*)d_in[7];
  const float* beta    = (const float*)d_in[8];
  const float* kpts    = (const float*)d_in[9];
  float* x = (float*)d_out;

  char* ws = (char*)d_ws;
  _Float16* featH = (_Float16*)ws;                  // 8,388,608 B
  _Float16* owt   = (_Float16*)(ws + 8388608);      //   131,072 B
  _Float16* wt    = (_Float16*)(ws + 8519680);      //   131,072 B
  float*    stats = (float*)(ws + 8650752);         //       512 B

  k_prep<<<4160, 256, 0, stream>>>(oweight, weight, feat, owt, wt, featH, stats);
  k_fused<<<4096, 256, 0, stream>>>(query, support, nidx, featH, kpts, obias,
                                    owt, wt, x, stats);
  k_norm<<<4096, 256, 0, stream>>>(x, stats, gamma, beta);
}